// Round 4
// baseline (3346.280 us; speedup 1.0000x reference)
//
#include <hip/hip_runtime.h>
#include <hip/hip_bf16.h>
#include <stdint.h>

// MoE head. Expert path: prepass bf16 conversion (x, We1^T), then a 256x256
// 8-wave MFMA GEMM using the m201-style phase schedule: per K-tile 4 phases,
// each {ds_read frags, stage half-unit via global_load_lds, s_barrier,
// setprio(1) 16xMFMA setprio(0), [vmcnt(8)], s_barrier}. Counted vmcnt keeps
// loads in flight across barriers (no full drain). Raw s_barrier with NO
// sched_barrier walls / memory clobbers (m141: order-pinning = -40%).
// Fused relu*We2 epilogue. Gate path: 3-term bf16 split GEMM. Finalize:
// reduce partials, top-2, renormalized softmax combine.

#define B_DIM  16384
#define H_DIM  4096
#define H2_DIM 2048
#define E_DIM  8

typedef __attribute__((ext_vector_type(8))) short short8;
typedef __attribute__((ext_vector_type(4))) float f32x4;

static __device__ __forceinline__ unsigned int bf16_rn(float f) {
    unsigned int u = __builtin_bit_cast(unsigned int, f);
    u += 0x7FFFu + ((u >> 16) & 1u);
    return u >> 16;
}
static __device__ __forceinline__ float bf16f(unsigned int h) {
    unsigned int u = h << 16;
    return __builtin_bit_cast(float, u);
}

static __device__ __forceinline__ void gload_lds16(const void* g, void* l) {
    __builtin_amdgcn_global_load_lds(
        (const __attribute__((address_space(1))) unsigned int*)g,
        (__attribute__((address_space(3))) unsigned int*)l,
        16, 0, 0);
}

// ---------------------------------------------------------------------------
// Prepass 1: x fp32 -> bf16 (RNE), linear layout.
// ---------------------------------------------------------------------------
__global__ __launch_bounds__(256) void convert_x_bf16(
    const float* __restrict__ x, unsigned short* __restrict__ xb)
{
    const size_t n8 = (size_t)B_DIM * H_DIM / 8;
    for (size_t i = (size_t)blockIdx.x * 256 + threadIdx.x; i < n8;
         i += (size_t)gridDim.x * 256) {
        const f32x4* p = reinterpret_cast<const f32x4*>(x) + 2 * i;
        f32x4 a = p[0], b = p[1];
        uint4 o;
        o.x = bf16_rn(a[0]) | (bf16_rn(a[1]) << 16);
        o.y = bf16_rn(a[2]) | (bf16_rn(a[3]) << 16);
        o.z = bf16_rn(b[0]) | (bf16_rn(b[1]) << 16);
        o.w = bf16_rn(b[2]) | (bf16_rn(b[3]) << 16);
        reinterpret_cast<uint4*>(xb)[i] = o;
    }
}

// ---------------------------------------------------------------------------
// Prepass 2: We1[e][h][d] fp32 -> w1t[e][d][h] bf16 (64x64 LDS tile transpose)
// ---------------------------------------------------------------------------
__global__ __launch_bounds__(256) void transpose_We1_bf16(
    const float* __restrict__ We1, unsigned short* __restrict__ w1t)
{
    __shared__ unsigned short t[64 * 66];
    const int tid = threadIdx.x;
    const int h0 = blockIdx.x * 64, d0 = blockIdx.y * 64;
    const int e = blockIdx.z;
    const float* src = We1 + ((size_t)e * H_DIM + h0) * H2_DIM + d0;
#pragma unroll
    for (int j = 0; j < 16; ++j) {
        const int row = (tid >> 6) + 4 * j;
        const int col = tid & 63;
        t[row * 66 + col] = (unsigned short)bf16_rn(src[(size_t)row * H2_DIM + col]);
    }
    __syncthreads();
    unsigned int* dst = reinterpret_cast<unsigned int*>(
        w1t + ((size_t)e * H2_DIM + d0) * H_DIM + h0);
#pragma unroll
    for (int j = 0; j < 8; ++j) {
        const int drow = (tid >> 5) + 8 * j;
        const int hp = tid & 31;
        unsigned int v = (unsigned int)t[(2 * hp) * 66 + drow]
                       | ((unsigned int)t[(2 * hp + 1) * 66 + drow] << 16);
        dst[(size_t)drow * (H_DIM / 2) + hp] = v;
    }
}

// ---------------------------------------------------------------------------
// Expert GEMM: 256x256 tile, BK=64, 8 waves, 4-phase schedule, counted vmcnt.
// LDS per operand: [2 buf][2 k-half][256 rows][32 k] bf16 (16 KB units).
// Stage schedule (tile t, buf c=t&1):
//   ph0: stage A.h1(t+1)->c^1   ph1: stage B.h1(t+1)->c^1  + vmcnt(8)
//   ph2: stage A.h0(t+2)->c     ph3: stage B.h0(t+2)->c    + vmcnt(8)
// Each staged region is dead (last read >=1 barrier before the stage issue).
// epart[b][e][chunk8] = sum_{d in 256-chunk} relu(x@We1 + be1) * We2
// ---------------------------------------------------------------------------
__global__ __launch_bounds__(512, 2) void moe_expert_gemm_256(
    const unsigned short* __restrict__ xb, const unsigned short* __restrict__ w1t,
    const float* __restrict__ be1, const float* __restrict__ We2,
    float* __restrict__ epart)
{
    __shared__ short lA[2][2][8192];   // 64 KB
    __shared__ short lB[2][2][8192];   // 64 KB
    __shared__ float red[4][256];      // 4 KB

    const int tid  = threadIdx.x;
    const int lane = tid & 63;
    const int wv   = tid >> 6;   // 0..7
    const int wm   = wv >> 2;    // 0..1
    const int wn   = wv & 3;     // 0..3

    // XCD-aware bijective swizzle (4096 % 8 == 0)
    const int lin = blockIdx.y * 64 + blockIdx.x;
    const int swz = (lin & 7) * 512 + (lin >> 3);
    const int bm  = swz >> 6;
    const int nb  = swz & 63;
    const int e = nb >> 3, chunk = nb & 7;
    const int dbase = chunk * 256;

    const char* Abase = (const char*)(xb + (size_t)bm * 256 * H_DIM);
    const char* Bbase = (const char*)(w1t + ((size_t)e * H2_DIM + dbase) * H_DIM);

    // staging map: chunk idx = rnd*512 + tid; row = idx>>2; stored slot = idx&3;
    // global kslot = slot ^ ((row>>1)&3)  (2-way-free bank swizzle)
    const int srow0 = tid >> 2;                              // rows 0..127 (rnd0)
    const int sks16 = (((tid & 3) ^ ((tid >> 3) & 3)) << 4); // same both rnds

#define STAGE_U(ARR, GB, TT, HH, CC) do {                                      \
    gload_lds16(GB + (size_t)srow0 * 8192 + (TT) * 128 + (HH) * 64 + sks16,    \
                (char*)&ARR[CC][HH][0] + wv * 1024);                           \
    gload_lds16(GB + (size_t)(srow0 + 128) * 8192 + (TT) * 128 + (HH) * 64 + sks16, \
                (char*)&ARR[CC][HH][0] + 8192 + wv * 1024);                    \
} while (0)

    // fragment read bases: row r, want global kslot = lane>>4
    // stored slot = (lane>>4) ^ ((r>>1)&3); invariant across mi/ni (+16 rows)
    const int rA = wm * 128 + (lane & 15);
    const int offA = rA * 64 + ((((lane >> 4)) ^ ((rA >> 1) & 3)) << 4);
    const int rB = wn * 64 + (lane & 15);
    const int offB = rB * 64 + ((((lane >> 4)) ^ ((rB >> 1) & 3)) << 4);

    f32x4 acc[8][4];
#pragma unroll
    for (int i = 0; i < 8; ++i)
#pragma unroll
        for (int j = 0; j < 4; ++j) acc[i][j] = (f32x4){0.f, 0.f, 0.f, 0.f};

    // prologue: tile0 all 4 units, tile1 half0 units (order matters for vmcnt)
    STAGE_U(lA, Abase, 0, 0, 0);
    STAGE_U(lB, Bbase, 0, 0, 0);
    STAGE_U(lA, Abase, 0, 1, 0);
    STAGE_U(lB, Bbase, 0, 1, 0);
    STAGE_U(lA, Abase, 1, 0, 1);
    STAGE_U(lB, Bbase, 1, 0, 1);
    asm volatile("s_waitcnt vmcnt(8)");
    __builtin_amdgcn_s_barrier();

    for (int t = 0; t < 64; ++t) {
        const int c = t & 1;
        const int tn1 = (t + 1 < 64) ? t + 1 : 63;
        const int tn2 = (t + 2 < 64) ? t + 2 : 63;
        const char* lAc0 = (const char*)&lA[c][0][0];
        const char* lAc1 = (const char*)&lA[c][1][0];
        const char* lBc0 = (const char*)&lB[c][0][0];
        const char* lBc1 = (const char*)&lB[c][1][0];
        short8 bfr[4], af[4];

        // ---- ph0: kk=0, mi 0-3 ----
#pragma unroll
        for (int ni = 0; ni < 4; ++ni)
            bfr[ni] = *(const short8*)(lBc0 + offB + ni * 1024);
#pragma unroll
        for (int i = 0; i < 4; ++i)
            af[i] = *(const short8*)(lAc0 + offA + i * 1024);
        STAGE_U(lA, Abase, tn1, 1, c ^ 1);
        __builtin_amdgcn_s_barrier();
        __builtin_amdgcn_s_setprio(1);
#pragma unroll
        for (int i = 0; i < 4; ++i)
#pragma unroll
            for (int ni = 0; ni < 4; ++ni)
                acc[i][ni] = __builtin_amdgcn_mfma_f32_16x16x32_bf16(af[i], bfr[ni], acc[i][ni], 0, 0, 0);
        __builtin_amdgcn_s_setprio(0);
        __builtin_amdgcn_s_barrier();

        // ---- ph1: kk=0, mi 4-7 ----
#pragma unroll
        for (int i = 0; i < 4; ++i)
            af[i] = *(const short8*)(lAc0 + offA + (4 + i) * 1024);
        STAGE_U(lB, Bbase, tn1, 1, c ^ 1);
        __builtin_amdgcn_s_barrier();
        __builtin_amdgcn_s_setprio(1);
#pragma unroll
        for (int i = 0; i < 4; ++i)
#pragma unroll
            for (int ni = 0; ni < 4; ++ni)
                acc[4 + i][ni] = __builtin_amdgcn_mfma_f32_16x16x32_bf16(af[i], bfr[ni], acc[4 + i][ni], 0, 0, 0);
        __builtin_amdgcn_s_setprio(0);
        asm volatile("s_waitcnt vmcnt(8)");
        __builtin_amdgcn_s_barrier();

        // ---- ph2: kk=1, mi 0-3 ----
#pragma unroll
        for (int ni = 0; ni < 4; ++ni)
            bfr[ni] = *(const short8*)(lBc1 + offB + ni * 1024);
#pragma unroll
        for (int i = 0; i < 4; ++i)
            af[i] = *(const short8*)(lAc1 + offA + i * 1024);
        STAGE_U(lA, Abase, tn2, 0, c);
        __builtin_amdgcn_s_barrier();
        __builtin_amdgcn_s_setprio(1);
#pragma unroll
        for (int i = 0; i < 4; ++i)
#pragma unroll
            for (int ni = 0; ni < 4; ++ni)
                acc[i][ni] = __builtin_amdgcn_mfma_f32_16x16x32_bf16(af[i], bfr[ni], acc[i][ni], 0, 0, 0);
        __builtin_amdgcn_s_setprio(0);
        __builtin_amdgcn_s_barrier();

        // ---- ph3: kk=1, mi 4-7 ----
#pragma unroll
        for (int i = 0; i < 4; ++i)
            af[i] = *(const short8*)(lAc1 + offA + (4 + i) * 1024);
        STAGE_U(lB, Bbase, tn2, 0, c);
        __builtin_amdgcn_s_barrier();
        __builtin_amdgcn_s_setprio(1);
#pragma unroll
        for (int i = 0; i < 4; ++i)
#pragma unroll
            for (int ni = 0; ni < 4; ++ni)
                acc[4 + i][ni] = __builtin_amdgcn_mfma_f32_16x16x32_bf16(af[i], bfr[ni], acc[4 + i][ni], 0, 0, 0);
        __builtin_amdgcn_s_setprio(0);
        asm volatile("s_waitcnt vmcnt(8)");
        __builtin_amdgcn_s_barrier();
    }
#undef STAGE_U

    // epilogue: relu(acc + be1) * We2, reduce over this wave's 64 d-cols
    const int cc = lane & 15, g = lane >> 4;
    float w2v[4], b1v[4];
#pragma unroll
    for (int ni = 0; ni < 4; ++ni) {
        const int d = dbase + wn * 64 + ni * 16 + cc;
        b1v[ni] = be1[e * H2_DIM + d];
        w2v[ni] = We2[e * H2_DIM + d];
    }
#pragma unroll
    for (int mi = 0; mi < 8; ++mi) {
#pragma unroll
        for (int r = 0; r < 4; ++r) {
            float s = 0.f;
#pragma unroll
            for (int ni = 0; ni < 4; ++ni) {
                float v = acc[mi][ni][r] + b1v[ni];
                v = fmaxf(v, 0.f);
                s = fmaf(v, w2v[ni], s);
            }
            s += __shfl_xor(s, 1);
            s += __shfl_xor(s, 2);
            s += __shfl_xor(s, 4);
            s += __shfl_xor(s, 8);
            if (cc == 0) red[wn][wm * 128 + mi * 16 + g * 4 + r] = s;
        }
    }
    __syncthreads();
    if (tid < 256) {
        const int b = bm * 256 + tid;
        epart[((size_t)b * E_DIM + e) * 8 + chunk] =
            red[0][tid] + red[1][tid] + red[2][tid] + red[3][tid];
    }
}

// ---------------------------------------------------------------------------
// Expert GEMM (fallback, fp32 in-kernel conversion) — round-1 verified.
// Writes epart [b][e][16].
// ---------------------------------------------------------------------------
__global__ __launch_bounds__(256, 2) void moe_expert_gemm(
    const float* __restrict__ x, const float* __restrict__ We1,
    const float* __restrict__ be1, const float* __restrict__ We2,
    float* __restrict__ epart)
{
    __shared__ short lA[128 * 64];
    __shared__ short lB[128 * 64];
    __shared__ float red[2][128];

    const int tid  = threadIdx.x;
    const int lane = tid & 63;
    const int wm   = (tid >> 6) >> 1;
    const int wn   = (tid >> 6) & 1;
    const int nb = blockIdx.x, bm = blockIdx.y;
    const int e = nb >> 4, chunk = nb & 15;
    const int dbase = chunk * 128;

    const float* Asrc = x + (size_t)bm * 128 * H_DIM;
    const float* Bsrc = We1 + (size_t)e * H_DIM * H2_DIM + dbase;

    f32x4 acc[4][4];
#pragma unroll
    for (int i = 0; i < 4; ++i)
#pragma unroll
        for (int j = 0; j < 4; ++j) acc[i][j] = (f32x4){0.f, 0.f, 0.f, 0.f};

    const int arow0 = tid >> 4, af4 = tid & 15;
    const int bn = tid & 127, bkc0 = tid >> 7;

    for (int k0 = 0; k0 < H_DIM; k0 += 64) {
        __syncthreads();
#pragma unroll
        for (int j = 0; j < 8; ++j) {
            const int row = arow0 + j * 16;
            const float* p = Asrc + (size_t)row * H_DIM + k0 + af4 * 4;
            float a0 = p[0], a1 = p[1], a2 = p[2], a3 = p[3];
            uint2 wv2;
            wv2.x = bf16_rn(a0) | (bf16_rn(a1) << 16);
            wv2.y = bf16_rn(a2) | (bf16_rn(a3) << 16);
            const int byte = row * 128 + ((af4 * 8) ^ ((row & 7) << 4));
            *reinterpret_cast<uint2*>(reinterpret_cast<char*>(lA) + byte) = wv2;
        }
#pragma unroll
        for (int j = 0; j < 4; ++j) {
            const int kc = bkc0 + 2 * j;
            const float* p = Bsrc + (size_t)(k0 + kc * 8) * H2_DIM + bn;
            uint4 wv4;
            wv4.x = bf16_rn(p[0])          | (bf16_rn(p[H2_DIM])     << 16);
            wv4.y = bf16_rn(p[2 * H2_DIM]) | (bf16_rn(p[3 * H2_DIM]) << 16);
            wv4.z = bf16_rn(p[4 * H2_DIM]) | (bf16_rn(p[5 * H2_DIM]) << 16);
            wv4.w = bf16_rn(p[6 * H2_DIM]) | (bf16_rn(p[7 * H2_DIM]) << 16);
            const int byte = bn * 128 + ((kc * 16) ^ ((bn & 7) << 4));
            *reinterpret_cast<uint4*>(reinterpret_cast<char*>(lB) + byte) = wv4;
        }
        __syncthreads();
#pragma unroll
        for (int kk = 0; kk < 2; ++kk) {
            const int kbyte = kk * 64 + ((lane >> 4) << 4);
            short8 af[4], bfr[4];
#pragma unroll
            for (int mi = 0; mi < 4; ++mi) {
                const int r = wm * 64 + mi * 16 + (lane & 15);
                af[mi] = *reinterpret_cast<const short8*>(
                    reinterpret_cast<const char*>(lA) + r * 128 + (kbyte ^ ((r & 7) << 4)));
            }
#pragma unroll
            for (int ni = 0; ni < 4; ++ni) {
                const int r = wn * 64 + ni * 16 + (lane & 15);
                bfr[ni] = *reinterpret_cast<const short8*>(
                    reinterpret_cast<const char*>(lB) + r * 128 + (kbyte ^ ((r & 7) << 4)));
            }
#pragma unroll
            for (int mi = 0; mi < 4; ++mi)
#pragma unroll
                for (int ni = 0; ni < 4; ++ni)
                    acc[mi][ni] = __builtin_amdgcn_mfma_f32_16x16x32_bf16(
                        af[mi], bfr[ni], acc[mi][ni], 0, 0, 0);
        }
    }

    const int c = lane & 15, g = lane >> 4;
    float w2v[4], b1v[4];
#pragma unroll
    for (int ni = 0; ni < 4; ++ni) {
        const int d = dbase + wn * 64 + ni * 16 + c;
        b1v[ni] = be1[e * H2_DIM + d];
        w2v[ni] = We2[e * H2_DIM + d];
    }
#pragma unroll
    for (int mi = 0; mi < 4; ++mi) {
#pragma unroll
        for (int r = 0; r < 4; ++r) {
            float s = 0.f;
#pragma unroll
            for (int ni = 0; ni < 4; ++ni) {
                float v = acc[mi][ni][r] + b1v[ni];
                v = fmaxf(v, 0.f);
                s = fmaf(v, w2v[ni], s);
            }
            s += __shfl_xor(s, 1);
            s += __shfl_xor(s, 2);
            s += __shfl_xor(s, 4);
            s += __shfl_xor(s, 8);
            if (c == 0) red[wn][wm * 64 + mi * 16 + g * 4 + r] = s;
        }
    }
    __syncthreads();
    if (tid < 128) {
        const int b = bm * 128 + tid;
        epart[((size_t)b * E_DIM + e) * 16 + chunk] = red[0][tid] + red[1][tid];
    }
}

// ---------------------------------------------------------------------------
// Gate GEMM, 3-term bf16 split for ~fp32 accuracy (top-k must match ref).
// ---------------------------------------------------------------------------
__global__ __launch_bounds__(256, 2) void moe_gate_gemm(
    const float* __restrict__ x, const float* __restrict__ Wg1,
    const float* __restrict__ bg1, const float* __restrict__ Wg2,
    float* __restrict__ gpart)
{
    __shared__ short lAh[128 * 64], lAl[128 * 64];
    __shared__ short lBh[128 * 64], lBl[128 * 64];
    __shared__ float lW2[128 * 8];
    __shared__ float gred[2][128][8];

    const int tid  = threadIdx.x;
    const int lane = tid & 63;
    const int wm = (tid >> 6) >> 1, wn = (tid >> 6) & 1;
    const int nb = blockIdx.x, bm = blockIdx.y;
    const int dbase = nb * 128;

    const float* Asrc = x + (size_t)bm * 128 * H_DIM;
    const float* Bsrc = Wg1 + dbase;

    {
        const f32x4* s = reinterpret_cast<const f32x4*>(Wg2 + (size_t)dbase * 8);
        reinterpret_cast<f32x4*>(lW2)[tid] = s[tid];
    }

    f32x4 acc[4][4];
#pragma unroll
    for (int i = 0; i < 4; ++i)
#pragma unroll
        for (int j = 0; j < 4; ++j) acc[i][j] = (f32x4){0.f, 0.f, 0.f, 0.f};

    const int arow0 = tid >> 4, af4 = tid & 15;
    const int bn = tid & 127, bkc0 = tid >> 7;

    for (int k0 = 0; k0 < H_DIM; k0 += 64) {
        __syncthreads();
#pragma unroll
        for (int j = 0; j < 8; ++j) {
            const int row = arow0 + j * 16;
            const float* p = Asrc + (size_t)row * H_DIM + k0 + af4 * 4;
            float a[4] = {p[0], p[1], p[2], p[3]};
            unsigned int hb[4], lb[4];
#pragma unroll
            for (int q = 0; q < 4; ++q) {
                hb[q] = bf16_rn(a[q]);
                lb[q] = bf16_rn(a[q] - bf16f(hb[q]));
            }
            const int byte = row * 128 + ((af4 * 8) ^ ((row & 7) << 4));
            *reinterpret_cast<uint2*>(reinterpret_cast<char*>(lAh) + byte) =
                make_uint2(hb[0] | (hb[1] << 16), hb[2] | (hb[3] << 16));
            *reinterpret_cast<uint2*>(reinterpret_cast<char*>(lAl) + byte) =
                make_uint2(lb[0] | (lb[1] << 16), lb[2] | (lb[3] << 16));
        }
#pragma unroll
        for (int j = 0; j < 4; ++j) {
            const int kc = bkc0 + 2 * j;
            const float* p = Bsrc + (size_t)(k0 + kc * 8) * H2_DIM + bn;
            unsigned int hb[8], lb[8];
#pragma unroll
            for (int q = 0; q < 8; ++q) {
                float v = p[(size_t)q * H2_DIM];
                hb[q] = bf16_rn(v);
                lb[q] = bf16_rn(v - bf16f(hb[q]));
            }
            const int byte = bn * 128 + ((kc * 16) ^ ((bn & 7) << 4));
            *reinterpret_cast<uint4*>(reinterpret_cast<char*>(lBh) + byte) =
                make_uint4(hb[0] | (hb[1] << 16), hb[2] | (hb[3] << 16),
                           hb[4] | (hb[5] << 16), hb[6] | (hb[7] << 16));
            *reinterpret_cast<uint4*>(reinterpret_cast<char*>(lBl) + byte) =
                make_uint4(lb[0] | (lb[1] << 16), lb[2] | (lb[3] << 16),
                           lb[4] | (lb[5] << 16), lb[6] | (lb[7] << 16));
        }
        __syncthreads();
#pragma unroll
        for (int kk = 0; kk < 2; ++kk) {
            const int kbyte = kk * 64 + ((lane >> 4) << 4);
            short8 ah[4], al[4], bh[4], bl[4];
#pragma unroll
            for (int mi = 0; mi < 4; ++mi) {
                const int r = wm * 64 + mi * 16 + (lane & 15);
                const int off = r * 128 + (kbyte ^ ((r & 7) << 4));
                ah[mi] = *reinterpret_cast<const short8*>(reinterpret_cast<const char*>(lAh) + off);
                al[mi] = *reinterpret_cast<const short8*>(reinterpret_cast<const char*>(lAl) + off);
            }
#pragma unroll
            for (int ni = 0; ni < 4; ++ni) {
                const int r = wn * 64 + ni * 16 + (lane & 15);
                const int off = r * 128 + (kbyte ^ ((r & 7) << 4));
                bh[ni] = *reinterpret_cast<const short8*>(reinterpret_cast<const char*>(lBh) + off);
                bl[ni] = *reinterpret_cast<const short8*>(reinterpret_cast<const char*>(lBl) + off);
            }
#pragma unroll
            for (int mi = 0; mi < 4; ++mi)
#pragma unroll
                for (int ni = 0; ni < 4; ++ni) {
                    acc[mi][ni] = __builtin_amdgcn_mfma_f32_16x16x32_bf16(ah[mi], bh[ni], acc[mi][ni], 0, 0, 0);
                    acc[mi][ni] = __builtin_amdgcn_mfma_f32_16x16x32_bf16(ah[mi], bl[ni], acc[mi][ni], 0, 0, 0);
                    acc[mi][ni] = __builtin_amdgcn_mfma_f32_16x16x32_bf16(al[mi], bh[ni], acc[mi][ni], 0, 0, 0);
                }
        }
    }

    const int c = lane & 15, g = lane >> 4;
    float bgv[4];
#pragma unroll
    for (int ni = 0; ni < 4; ++ni) bgv[ni] = bg1[dbase + wn * 64 + ni * 16 + c];
#pragma unroll
    for (int mi = 0; mi < 4; ++mi) {
#pragma unroll
        for (int r = 0; r < 4; ++r) {
            float gv[4];
#pragma unroll
            for (int ni = 0; ni < 4; ++ni)
                gv[ni] = fmaxf(acc[mi][ni][r] + bgv[ni], 0.f);
#pragma unroll
            for (int e8 = 0; e8 < 8; ++e8) {
                float t = 0.f;
#pragma unroll
                for (int ni = 0; ni < 4; ++ni)
                    t = fmaf(gv[ni], lW2[(wn * 64 + ni * 16 + c) * 8 + e8], t);
                t += __shfl_xor(t, 1);
                t += __shfl_xor(t, 2);
                t += __shfl_xor(t, 4);
                t += __shfl_xor(t, 8);
                if (c == e8) gred[wn][wm * 64 + mi * 16 + g * 4 + r][e8] = t;
            }
        }
    }
    __syncthreads();
    {
        const int row = tid & 127;
        const int ebase = (tid >> 7) * 4;
        const int b = bm * 128 + row;
#pragma unroll
        for (int i = 0; i < 4; ++i) {
            const int e8 = ebase + i;
            gpart[(size_t)b * 128 + nb * 8 + e8] = gred[0][row][e8] + gred[1][row][e8];
        }
    }
}

// ---------------------------------------------------------------------------
// Finalize: reduce partials, softmax top-2 (renormalized), combine.
// ---------------------------------------------------------------------------
template <int NC>
__global__ __launch_bounds__(256) void moe_finalize(
    const float* __restrict__ gpart, const float* __restrict__ epart,
    const float* __restrict__ bg2, const float* __restrict__ be2,
    float* __restrict__ out)
{
    const int b = blockIdx.x * 256 + threadIdx.x;
    float logit[8];
#pragma unroll
    for (int e = 0; e < 8; ++e) logit[e] = bg2[e];
    const float* gp = gpart + (size_t)b * 128;
#pragma unroll
    for (int cN = 0; cN < 16; ++cN)
#pragma unroll
        for (int e = 0; e < 8; ++e) logit[e] += gp[cN * 8 + e];

    float eo[8];
    const float* ep = epart + (size_t)b * E_DIM * NC;
#pragma unroll
    for (int e = 0; e < 8; ++e) {
        float s = be2[e];
#pragma unroll
        for (int cN = 0; cN < NC; ++cN) s += ep[e * NC + cN];
        eo[e] = s;
    }

    int i1 = 0; float m1 = logit[0];
#pragma unroll
    for (int e = 1; e < 8; ++e) if (logit[e] > m1) { m1 = logit[e]; i1 = e; }
    int i2 = -1; float m2 = -3.4e38f;
#pragma unroll
    for (int e = 0; e < 8; ++e) if (e != i1 && logit[e] > m2) { m2 = logit[e]; i2 = e; }

    const float w2 = expf(m2 - m1);
    out[b] = (eo[i1] + w2 * eo[i2]) / (1.f + w2);
}

// ---------------------------------------------------------------------------
extern "C" void kernel_launch(void* const* d_in, const int* in_sizes, int n_in,
                              void* d_out, int out_size, void* d_ws, size_t ws_size,
                              hipStream_t stream) {
    (void)in_sizes; (void)n_in; (void)out_size;
    const float* x   = (const float*)d_in[0];
    const float* We1 = (const float*)d_in[1];
    const float* be1 = (const float*)d_in[2];
    const float* We2 = (const float*)d_in[3];
    const float* be2 = (const float*)d_in[4];
    const float* Wg1 = (const float*)d_in[5];
    const float* bg1 = (const float*)d_in[6];
    const float* Wg2 = (const float*)d_in[7];
    const float* bg2 = (const float*)d_in[8];
    float* out = (float*)d_out;

    char* ws = (char*)d_ws;
    size_t off = 0;
    float* gpart = (float*)(ws + off);                 off += (size_t)B_DIM * 128 * 4;            // 8 MB
    float* epart = (float*)(ws + off);                 off += (size_t)B_DIM * 128 * 4;            // 8 MB (max of both layouts)
    unsigned short* xb  = (unsigned short*)(ws + off); off += (size_t)B_DIM * H_DIM * 2;          // 128 MB
    unsigned short* w1t = (unsigned short*)(ws + off); off += (size_t)E_DIM * H2_DIM * H_DIM * 2; // 128 MB
    const size_t NEED = off;

    if (ws_size >= NEED) {
        convert_x_bf16<<<4096, 256, 0, stream>>>(x, xb);
        transpose_We1_bf16<<<dim3(64, 32, 8), 256, 0, stream>>>(We1, w1t);
        moe_expert_gemm_256<<<dim3(64, 64), 512, 0, stream>>>(xb, w1t, be1, We2, epart);
        moe_gate_gemm<<<dim3(16, 128), 256, 0, stream>>>(x, Wg1, bg1, Wg2, gpart);
        moe_finalize<8><<<64, 256, 0, stream>>>(gpart, epart, bg2, be2, out);
    } else {
        moe_expert_gemm<<<dim3(128, 128), 256, 0, stream>>>(x, We1, be1, We2, epart);
        moe_gate_gemm<<<dim3(16, 128), 256, 0, stream>>>(x, Wg1, bg1, Wg2, gpart);
        moe_finalize<16><<<64, 256, 0, stream>>>(gpart, epart, bg2, be2, out);
    }
}

// Round 6
// 3118.320 us; speedup vs baseline: 1.0731x; 1.0731x over previous
//
#include <hip/hip_runtime.h>
#include <hip/hip_bf16.h>
#include <stdint.h>

// MoE head. Expert path: prepasses build PRE-SWIZZLED bf16 staging panels
// (16 KB units = exactly one global_load_lds stage, contiguous) for x and
// We1^T; 256x256 8-wave MFMA GEMM with m201-style 4-phase schedule, counted
// vmcnt, setprio, and 2-level (L3 batch / L2 XCD) temporal block mapping.
// Gate path: 3-term bf16 split GEMM (fp32-class accuracy for top-k).
// Finalize: reduce partials, top-2, renormalized softmax combine.
// R6 fix: build_w1B_panels grid x-dim is 32 (= H2/64), not 64 (R5 wrote OOB).

#define B_DIM  16384
#define H_DIM  4096
#define H2_DIM 2048
#define E_DIM  8

typedef __attribute__((ext_vector_type(8))) short short8;
typedef __attribute__((ext_vector_type(4))) float f32x4;

static __device__ __forceinline__ unsigned int bf16_rn(float f) {
    unsigned int u = __builtin_bit_cast(unsigned int, f);
    u += 0x7FFFu + ((u >> 16) & 1u);
    return u >> 16;
}
static __device__ __forceinline__ float bf16f(unsigned int h) {
    unsigned int u = h << 16;
    return __builtin_bit_cast(float, u);
}

static __device__ __forceinline__ void gload_lds16(const void* g, void* l) {
    __builtin_amdgcn_global_load_lds(
        (const __attribute__((address_space(1))) unsigned int*)g,
        (__attribute__((address_space(3))) unsigned int*)l,
        16, 0, 0);
}

// ---------------------------------------------------------------------------
// Prepass 1: x fp32 -> panel layout panA[bm(64)][t(64)][h(2)]{16KB unit}.
// Unit internal: [row(256)][slot(4)]{8 bf16}, stored slot = kslot ^ ((row>>1)&3)
// (same swizzle the GEMM's ds_reads expect; staging is then a linear copy).
// ---------------------------------------------------------------------------
__global__ __launch_bounds__(256) void build_xA_panels(
    const float* __restrict__ x, unsigned short* __restrict__ panA)
{
    const int t = blockIdx.x, bm = blockIdx.y, tid = threadIdx.x;
    const size_t ubase = (size_t)(bm * 64 + t) * 2 * 8192;   // elems (h=0)
#pragma unroll
    for (int u = 0; u < 8; ++u) {
        const int gid = u * 256 + tid;
        const int h = gid >> 10, rem = gid & 1023;
        const int row = rem >> 2, slot = rem & 3;
        const int kslot = slot ^ ((row >> 1) & 3);
        const float* s = x + (size_t)(bm * 256 + row) * H_DIM
                           + t * 64 + h * 32 + kslot * 8;
        f32x4 a = ((const f32x4*)s)[0], b = ((const f32x4*)s)[1];
        uint4 o;
        o.x = bf16_rn(a[0]) | (bf16_rn(a[1]) << 16);
        o.y = bf16_rn(a[2]) | (bf16_rn(a[3]) << 16);
        o.z = bf16_rn(b[0]) | (bf16_rn(b[1]) << 16);
        o.w = bf16_rn(b[2]) | (bf16_rn(b[3]) << 16);
        *(uint4*)(panA + ubase + (size_t)h * 8192 + row * 32 + slot * 8) = o;
    }
}

// ---------------------------------------------------------------------------
// Prepass 2: We1[e][k][d] fp32 -> panB[nbG(64)][t(64)][h(2)]{16KB unit},
// unit internal [col(256)][slot(4)]{8 bf16 along k}, same swizzle.
// LDS 64x64 tile transpose per (e, t, dblk).  dblk in [0,32) = H2/64.
// ---------------------------------------------------------------------------
__global__ __launch_bounds__(256) void build_w1B_panels(
    const float* __restrict__ We1, unsigned short* __restrict__ panB)
{
    __shared__ unsigned short tile[64][72];
    const int dblk = blockIdx.x, t = blockIdx.y, e = blockIdx.z;
    const int tid = threadIdx.x;
    {
        const int kr = tid >> 2, c0 = (tid & 3) * 16;
        const float* s = We1 + ((size_t)e * H_DIM + t * 64 + kr) * H2_DIM
                             + dblk * 64 + c0;
#pragma unroll
        for (int q = 0; q < 4; ++q) {
            f32x4 v = ((const f32x4*)s)[q];
            tile[kr][c0 + q * 4 + 0] = (unsigned short)bf16_rn(v[0]);
            tile[kr][c0 + q * 4 + 1] = (unsigned short)bf16_rn(v[1]);
            tile[kr][c0 + q * 4 + 2] = (unsigned short)bf16_rn(v[2]);
            tile[kr][c0 + q * 4 + 3] = (unsigned short)bf16_rn(v[3]);
        }
    }
    __syncthreads();
    const int nbG = e * 8 + (dblk >> 2);
    const int col = tid >> 2, slot = tid & 3;
    const int colg = (dblk & 3) * 64 + col;
    const int kslot = slot ^ ((colg >> 1) & 3);
#pragma unroll
    for (int hh = 0; hh < 2; ++hh) {
        const int kl = hh * 32 + kslot * 8;
        uint4 o;
        o.x = (unsigned int)tile[kl + 0][col] | ((unsigned int)tile[kl + 1][col] << 16);
        o.y = (unsigned int)tile[kl + 2][col] | ((unsigned int)tile[kl + 3][col] << 16);
        o.z = (unsigned int)tile[kl + 4][col] | ((unsigned int)tile[kl + 5][col] << 16);
        o.w = (unsigned int)tile[kl + 6][col] | ((unsigned int)tile[kl + 7][col] << 16);
        *(uint4*)(panB + (((size_t)nbG * 64 + t) * 2 + hh) * 8192
                        + colg * 32 + slot * 8) = o;
    }
}

// ---------------------------------------------------------------------------
// Expert GEMM: 256x256 tile, BK=64, 8 waves, 4-phase schedule, counted vmcnt.
// Staging = contiguous 16KB panel units (perfectly coalesced global_load_lds).
// Block mapping: 16 temporal batches of (16bm x 16nb) [L3: 64 MB/batch];
// within batch each XCD gets an 8bm x 4nb sub-tile [L2: 384 KB/K-step].
// epart[b][e][chunk8] = sum_{d in 256-chunk} relu(x@We1 + be1) * We2
// ---------------------------------------------------------------------------
__global__ __launch_bounds__(512, 2) void moe_expert_gemm_256(
    const unsigned short* __restrict__ panA, const unsigned short* __restrict__ panB,
    const float* __restrict__ be1, const float* __restrict__ We2,
    float* __restrict__ epart)
{
    __shared__ short lA[2][2][8192];   // 64 KB
    __shared__ short lB[2][2][8192];   // 64 KB
    __shared__ float red[4][256];      // 4 KB

    const int tid  = threadIdx.x;
    const int lane = tid & 63;
    const int wv   = tid >> 6;   // 0..7
    const int wm   = wv >> 2;    // 0..1
    const int wn   = wv & 3;     // 0..3

    // 2-level temporal tiling (bijective): batch = 256 blocks = 16bm x 16nb
    const int lin = blockIdx.x;
    const int sb  = lin >> 8, i5 = lin & 255;
    const int sbm = sb & 3, snb = sb >> 2;
    const int xcd = i5 & 7, j5 = i5 >> 3;
    const int bm  = sbm * 16 + (xcd & 1) * 8 + (j5 & 7);
    const int nb  = snb * 16 + (xcd >> 1) * 4 + (j5 >> 3);
    const int e = nb >> 3, chunk = nb & 7;
    const int dbase = chunk * 256;

    const char* Abase = (const char*)panA + ((size_t)bm << 21);
    const char* Bbase = (const char*)panB + ((size_t)nb << 21);

#define STAGE_U(ARR, GB, TT, HH, CC) do {                                      \
    const char* u_ = GB + (((size_t)(TT) * 2 + (HH)) << 14);                   \
    gload_lds16(u_ + tid * 16, (char*)&ARR[CC][HH][0] + wv * 1024);            \
    gload_lds16(u_ + 8192 + tid * 16, (char*)&ARR[CC][HH][0] + 8192 + wv * 1024); \
} while (0)

    // fragment read bases: row r, global kslot = lane>>4,
    // stored slot = (lane>>4) ^ ((r>>1)&3)  (matches panel swizzle)
    const int rA = wm * 128 + (lane & 15);
    const int offA = rA * 64 + ((((lane >> 4)) ^ ((rA >> 1) & 3)) << 4);
    const int rB = wn * 64 + (lane & 15);
    const int offB = rB * 64 + ((((lane >> 4)) ^ ((rB >> 1) & 3)) << 4);

    f32x4 acc[8][4];
#pragma unroll
    for (int i = 0; i < 8; ++i)
#pragma unroll
        for (int j = 0; j < 4; ++j) acc[i][j] = (f32x4){0.f, 0.f, 0.f, 0.f};

    // prologue: tile0 all 4 units, tile1 half0 units
    STAGE_U(lA, Abase, 0, 0, 0);
    STAGE_U(lB, Bbase, 0, 0, 0);
    STAGE_U(lA, Abase, 0, 1, 0);
    STAGE_U(lB, Bbase, 0, 1, 0);
    STAGE_U(lA, Abase, 1, 0, 1);
    STAGE_U(lB, Bbase, 1, 0, 1);
    asm volatile("s_waitcnt vmcnt(8)");
    __builtin_amdgcn_s_barrier();

    for (int t = 0; t < 64; ++t) {
        const int c = t & 1;
        const int tn1 = (t + 1 < 64) ? t + 1 : 63;
        const int tn2 = (t + 2 < 64) ? t + 2 : 63;
        const char* lAc0 = (const char*)&lA[c][0][0];
        const char* lAc1 = (const char*)&lA[c][1][0];
        const char* lBc0 = (const char*)&lB[c][0][0];
        const char* lBc1 = (const char*)&lB[c][1][0];
        short8 bfr[4], af[4];

        // ---- ph0: kk=0, mi 0-3 ----
#pragma unroll
        for (int ni = 0; ni < 4; ++ni)
            bfr[ni] = *(const short8*)(lBc0 + offB + ni * 1024);
#pragma unroll
        for (int i = 0; i < 4; ++i)
            af[i] = *(const short8*)(lAc0 + offA + i * 1024);
        STAGE_U(lA, Abase, tn1, 1, c ^ 1);
        __builtin_amdgcn_s_barrier();
        __builtin_amdgcn_s_setprio(1);
#pragma unroll
        for (int i = 0; i < 4; ++i)
#pragma unroll
            for (int ni = 0; ni < 4; ++ni)
                acc[i][ni] = __builtin_amdgcn_mfma_f32_16x16x32_bf16(af[i], bfr[ni], acc[i][ni], 0, 0, 0);
        __builtin_amdgcn_s_setprio(0);
        __builtin_amdgcn_s_barrier();

        // ---- ph1: kk=0, mi 4-7 ----
#pragma unroll
        for (int i = 0; i < 4; ++i)
            af[i] = *(const short8*)(lAc0 + offA + (4 + i) * 1024);
        STAGE_U(lB, Bbase, tn1, 1, c ^ 1);
        __builtin_amdgcn_s_barrier();
        __builtin_amdgcn_s_setprio(1);
#pragma unroll
        for (int i = 0; i < 4; ++i)
#pragma unroll
            for (int ni = 0; ni < 4; ++ni)
                acc[4 + i][ni] = __builtin_amdgcn_mfma_f32_16x16x32_bf16(af[i], bfr[ni], acc[4 + i][ni], 0, 0, 0);
        __builtin_amdgcn_s_setprio(0);
        asm volatile("s_waitcnt vmcnt(8)");
        __builtin_amdgcn_s_barrier();

        // ---- ph2: kk=1, mi 0-3 ----
#pragma unroll
        for (int ni = 0; ni < 4; ++ni)
            bfr[ni] = *(const short8*)(lBc1 + offB + ni * 1024);
#pragma unroll
        for (int i = 0; i < 4; ++i)
            af[i] = *(const short8*)(lAc1 + offA + i * 1024);
        STAGE_U(lA, Abase, tn2, 0, c);
        __builtin_amdgcn_s_barrier();
        __builtin_amdgcn_s_setprio(1);
#pragma unroll
        for (int i = 0; i < 4; ++i)
#pragma unroll
            for (int ni = 0; ni < 4; ++ni)
                acc[i][ni] = __builtin_amdgcn_mfma_f32_16x16x32_bf16(af[i], bfr[ni], acc[i][ni], 0, 0, 0);
        __builtin_amdgcn_s_setprio(0);
        __builtin_amdgcn_s_barrier();

        // ---- ph3: kk=1, mi 4-7 ----
#pragma unroll
        for (int i = 0; i < 4; ++i)
            af[i] = *(const short8*)(lAc1 + offA + (4 + i) * 1024);
        STAGE_U(lB, Bbase, tn2, 0, c);
        __builtin_amdgcn_s_barrier();
        __builtin_amdgcn_s_setprio(1);
#pragma unroll
        for (int i = 0; i < 4; ++i)
#pragma unroll
            for (int ni = 0; ni < 4; ++ni)
                acc[4 + i][ni] = __builtin_amdgcn_mfma_f32_16x16x32_bf16(af[i], bfr[ni], acc[4 + i][ni], 0, 0, 0);
        __builtin_amdgcn_s_setprio(0);
        asm volatile("s_waitcnt vmcnt(8)");
        __builtin_amdgcn_s_barrier();
    }
#undef STAGE_U

    // epilogue: relu(acc + be1) * We2, reduce over this wave's 64 d-cols
    const int cc = lane & 15, g = lane >> 4;
    float w2v[4], b1v[4];
#pragma unroll
    for (int ni = 0; ni < 4; ++ni) {
        const int d = dbase + wn * 64 + ni * 16 + cc;
        b1v[ni] = be1[e * H2_DIM + d];
        w2v[ni] = We2[e * H2_DIM + d];
    }
#pragma unroll
    for (int mi = 0; mi < 8; ++mi) {
#pragma unroll
        for (int r = 0; r < 4; ++r) {
            float s = 0.f;
#pragma unroll
            for (int ni = 0; ni < 4; ++ni) {
                float v = acc[mi][ni][r] + b1v[ni];
                v = fmaxf(v, 0.f);
                s = fmaf(v, w2v[ni], s);
            }
            s += __shfl_xor(s, 1);
            s += __shfl_xor(s, 2);
            s += __shfl_xor(s, 4);
            s += __shfl_xor(s, 8);
            if (cc == 0) red[wn][wm * 128 + mi * 16 + g * 4 + r] = s;
        }
    }
    __syncthreads();
    if (tid < 256) {
        const int b = bm * 256 + tid;
        epart[((size_t)b * E_DIM + e) * 8 + chunk] =
            red[0][tid] + red[1][tid] + red[2][tid] + red[3][tid];
    }
}

// ---------------------------------------------------------------------------
// Expert GEMM (fallback, fp32 in-kernel conversion) — round-1 verified.
// Writes epart [b][e][16].
// ---------------------------------------------------------------------------
__global__ __launch_bounds__(256, 2) void moe_expert_gemm(
    const float* __restrict__ x, const float* __restrict__ We1,
    const float* __restrict__ be1, const float* __restrict__ We2,
    float* __restrict__ epart)
{
    __shared__ short lA[128 * 64];
    __shared__ short lB[128 * 64];
    __shared__ float red[2][128];

    const int tid  = threadIdx.x;
    const int lane = tid & 63;
    const int wm   = (tid >> 6) >> 1;
    const int wn   = (tid >> 6) & 1;
    const int nb = blockIdx.x, bm = blockIdx.y;
    const int e = nb >> 4, chunk = nb & 15;
    const int dbase = chunk * 128;

    const float* Asrc = x + (size_t)bm * 128 * H_DIM;
    const float* Bsrc = We1 + (size_t)e * H_DIM * H2_DIM + dbase;

    f32x4 acc[4][4];
#pragma unroll
    for (int i = 0; i < 4; ++i)
#pragma unroll
        for (int j = 0; j < 4; ++j) acc[i][j] = (f32x4){0.f, 0.f, 0.f, 0.f};

    const int arow0 = tid >> 4, af4 = tid & 15;
    const int bn = tid & 127, bkc0 = tid >> 7;

    for (int k0 = 0; k0 < H_DIM; k0 += 64) {
        __syncthreads();
#pragma unroll
        for (int j = 0; j < 8; ++j) {
            const int row = arow0 + j * 16;
            const float* p = Asrc + (size_t)row * H_DIM + k0 + af4 * 4;
            float a0 = p[0], a1 = p[1], a2 = p[2], a3 = p[3];
            uint2 wv2;
            wv2.x = bf16_rn(a0) | (bf16_rn(a1) << 16);
            wv2.y = bf16_rn(a2) | (bf16_rn(a3) << 16);
            const int byte = row * 128 + ((af4 * 8) ^ ((row & 7) << 4));
            *reinterpret_cast<uint2*>(reinterpret_cast<char*>(lA) + byte) = wv2;
        }
#pragma unroll
        for (int j = 0; j < 4; ++j) {
            const int kc = bkc0 + 2 * j;
            const float* p = Bsrc + (size_t)(k0 + kc * 8) * H2_DIM + bn;
            uint4 wv4;
            wv4.x = bf16_rn(p[0])          | (bf16_rn(p[H2_DIM])     << 16);
            wv4.y = bf16_rn(p[2 * H2_DIM]) | (bf16_rn(p[3 * H2_DIM]) << 16);
            wv4.z = bf16_rn(p[4 * H2_DIM]) | (bf16_rn(p[5 * H2_DIM]) << 16);
            wv4.w = bf16_rn(p[6 * H2_DIM]) | (bf16_rn(p[7 * H2_DIM]) << 16);
            const int byte = bn * 128 + ((kc * 16) ^ ((bn & 7) << 4));
            *reinterpret_cast<uint4*>(reinterpret_cast<char*>(lB) + byte) = wv4;
        }
        __syncthreads();
#pragma unroll
        for (int kk = 0; kk < 2; ++kk) {
            const int kbyte = kk * 64 + ((lane >> 4) << 4);
            short8 af[4], bfr[4];
#pragma unroll
            for (int mi = 0; mi < 4; ++mi) {
                const int r = wm * 64 + mi * 16 + (lane & 15);
                af[mi] = *reinterpret_cast<const short8*>(
                    reinterpret_cast<const char*>(lA) + r * 128 + (kbyte ^ ((r & 7) << 4)));
            }
#pragma unroll
            for (int ni = 0; ni < 4; ++ni) {
                const int r = wn * 64 + ni * 16 + (lane & 15);
                bfr[ni] = *reinterpret_cast<const short8*>(
                    reinterpret_cast<const char*>(lB) + r * 128 + (kbyte ^ ((r & 7) << 4)));
            }
#pragma unroll
            for (int mi = 0; mi < 4; ++mi)
#pragma unroll
                for (int ni = 0; ni < 4; ++ni)
                    acc[mi][ni] = __builtin_amdgcn_mfma_f32_16x16x32_bf16(
                        af[mi], bfr[ni], acc[mi][ni], 0, 0, 0);
        }
    }

    const int c = lane & 15, g = lane >> 4;
    float w2v[4], b1v[4];
#pragma unroll
    for (int ni = 0; ni < 4; ++ni) {
        const int d = dbase + wn * 64 + ni * 16 + c;
        b1v[ni] = be1[e * H2_DIM + d];
        w2v[ni] = We2[e * H2_DIM + d];
    }
#pragma unroll
    for (int mi = 0; mi < 4; ++mi) {
#pragma unroll
        for (int r = 0; r < 4; ++r) {
            float s = 0.f;
#pragma unroll
            for (int ni = 0; ni < 4; ++ni) {
                float v = acc[mi][ni][r] + b1v[ni];
                v = fmaxf(v, 0.f);
                s = fmaf(v, w2v[ni], s);
            }
            s += __shfl_xor(s, 1);
            s += __shfl_xor(s, 2);
            s += __shfl_xor(s, 4);
            s += __shfl_xor(s, 8);
            if (c == 0) red[wn][wm * 64 + mi * 16 + g * 4 + r] = s;
        }
    }
    __syncthreads();
    if (tid < 128) {
        const int b = bm * 128 + tid;
        epart[((size_t)b * E_DIM + e) * 16 + chunk] = red[0][tid] + red[1][tid];
    }
}

// ---------------------------------------------------------------------------
// Gate GEMM, 3-term bf16 split for ~fp32 accuracy (top-k must match ref).
// ---------------------------------------------------------------------------
__global__ __launch_bounds__(256, 2) void moe_gate_gemm(
    const float* __restrict__ x, const float* __restrict__ Wg1,
    const float* __restrict__ bg1, const float* __restrict__ Wg2,
    float* __restrict__ gpart)
{
    __shared__ short lAh[128 * 64], lAl[128 * 64];
    __shared__ short lBh[128 * 64], lBl[128 * 64];
    __shared__ float lW2[128 * 8];
    __shared__ float gred[2][128][8];

    const int tid  = threadIdx.x;
    const int lane = tid & 63;
    const int wm = (tid >> 6) >> 1, wn = (tid >> 6) & 1;
    const int nb = blockIdx.x, bm = blockIdx.y;
    const int dbase = nb * 128;

    const float* Asrc = x + (size_t)bm * 128 * H_DIM;
    const float* Bsrc = Wg1 + dbase;

    {
        const f32x4* s = reinterpret_cast<const f32x4*>(Wg2 + (size_t)dbase * 8);
        reinterpret_cast<f32x4*>(lW2)[tid] = s[tid];
    }

    f32x4 acc[4][4];
#pragma unroll
    for (int i = 0; i < 4; ++i)
#pragma unroll
        for (int j = 0; j < 4; ++j) acc[i][j] = (f32x4){0.f, 0.f, 0.f, 0.f};

    const int arow0 = tid >> 4, af4 = tid & 15;
    const int bn = tid & 127, bkc0 = tid >> 7;

    for (int k0 = 0; k0 < H_DIM; k0 += 64) {
        __syncthreads();
#pragma unroll
        for (int j = 0; j < 8; ++j) {
            const int row = arow0 + j * 16;
            const float* p = Asrc + (size_t)row * H_DIM + k0 + af4 * 4;
            float a[4] = {p[0], p[1], p[2], p[3]};
            unsigned int hb[4], lb[4];
#pragma unroll
            for (int q = 0; q < 4; ++q) {
                hb[q] = bf16_rn(a[q]);
                lb[q] = bf16_rn(a[q] - bf16f(hb[q]));
            }
            const int byte = row * 128 + ((af4 * 8) ^ ((row & 7) << 4));
            *reinterpret_cast<uint2*>(reinterpret_cast<char*>(lAh) + byte) =
                make_uint2(hb[0] | (hb[1] << 16), hb[2] | (hb[3] << 16));
            *reinterpret_cast<uint2*>(reinterpret_cast<char*>(lAl) + byte) =
                make_uint2(lb[0] | (lb[1] << 16), lb[2] | (lb[3] << 16));
        }
#pragma unroll
        for (int j = 0; j < 4; ++j) {
            const int kc = bkc0 + 2 * j;
            const float* p = Bsrc + (size_t)(k0 + kc * 8) * H2_DIM + bn;
            unsigned int hb[8], lb[8];
#pragma unroll
            for (int q = 0; q < 8; ++q) {
                float v = p[(size_t)q * H2_DIM];
                hb[q] = bf16_rn(v);
                lb[q] = bf16_rn(v - bf16f(hb[q]));
            }
            const int byte = bn * 128 + ((kc * 16) ^ ((bn & 7) << 4));
            *reinterpret_cast<uint4*>(reinterpret_cast<char*>(lBh) + byte) =
                make_uint4(hb[0] | (hb[1] << 16), hb[2] | (hb[3] << 16),
                           hb[4] | (hb[5] << 16), hb[6] | (hb[7] << 16));
            *reinterpret_cast<uint4*>(reinterpret_cast<char*>(lBl) + byte) =
                make_uint4(lb[0] | (lb[1] << 16), lb[2] | (lb[3] << 16),
                           lb[4] | (lb[5] << 16), lb[6] | (lb[7] << 16));
        }
        __syncthreads();
#pragma unroll
        for (int kk = 0; kk < 2; ++kk) {
            const int kbyte = kk * 64 + ((lane >> 4) << 4);
            short8 ah[4], al[4], bh[4], bl[4];
#pragma unroll
            for (int mi = 0; mi < 4; ++mi) {
                const int r = wm * 64 + mi * 16 + (lane & 15);
                const int off = r * 128 + (kbyte ^ ((r & 7) << 4));
                ah[mi] = *reinterpret_cast<const short8*>(reinterpret_cast<const char*>(lAh) + off);
                al[mi] = *reinterpret_cast<const short8*>(reinterpret_cast<const char*>(lAl) + off);
            }
#pragma unroll
            for (int ni = 0; ni < 4; ++ni) {
                const int r = wn * 64 + ni * 16 + (lane & 15);
                const int off = r * 128 + (kbyte ^ ((r & 7) << 4));
                bh[ni] = *reinterpret_cast<const short8*>(reinterpret_cast<const char*>(lBh) + off);
                bl[ni] = *reinterpret_cast<const short8*>(reinterpret_cast<const char*>(lBl) + off);
            }
#pragma unroll
            for (int mi = 0; mi < 4; ++mi)
#pragma unroll
                for (int ni = 0; ni < 4; ++ni) {
                    acc[mi][ni] = __builtin_amdgcn_mfma_f32_16x16x32_bf16(ah[mi], bh[ni], acc[mi][ni], 0, 0, 0);
                    acc[mi][ni] = __builtin_amdgcn_mfma_f32_16x16x32_bf16(ah[mi], bl[ni], acc[mi][ni], 0, 0, 0);
                    acc[mi][ni] = __builtin_amdgcn_mfma_f32_16x16x32_bf16(al[mi], bh[ni], acc[mi][ni], 0, 0, 0);
                }
        }
    }

    const int c = lane & 15, g = lane >> 4;
    float bgv[4];
#pragma unroll
    for (int ni = 0; ni < 4; ++ni) bgv[ni] = bg1[dbase + wn * 64 + ni * 16 + c];
#pragma unroll
    for (int mi = 0; mi < 4; ++mi) {
#pragma unroll
        for (int r = 0; r < 4; ++r) {
            float gv[4];
#pragma unroll
            for (int ni = 0; ni < 4; ++ni)
                gv[ni] = fmaxf(acc[mi][ni][r] + bgv[ni], 0.f);
#pragma unroll
            for (int e8 = 0; e8 < 8; ++e8) {
                float t = 0.f;
#pragma unroll
                for (int ni = 0; ni < 4; ++ni)
                    t = fmaf(gv[ni], lW2[(wn * 64 + ni * 16 + c) * 8 + e8], t);
                t += __shfl_xor(t, 1);
                t += __shfl_xor(t, 2);
                t += __shfl_xor(t, 4);
                t += __shfl_xor(t, 8);
                if (c == e8) gred[wn][wm * 64 + mi * 16 + g * 4 + r][e8] = t;
            }
        }
    }
    __syncthreads();
    {
        const int row = tid & 127;
        const int ebase = (tid >> 7) * 4;
        const int b = bm * 128 + row;
#pragma unroll
        for (int i = 0; i < 4; ++i) {
            const int e8 = ebase + i;
            gpart[(size_t)b * 128 + nb * 8 + e8] = gred[0][row][e8] + gred[1][row][e8];
        }
    }
}

// ---------------------------------------------------------------------------
// Finalize: reduce partials, softmax top-2 (renormalized), combine.
// ---------------------------------------------------------------------------
template <int NC>
__global__ __launch_bounds__(256) void moe_finalize(
    const float* __restrict__ gpart, const float* __restrict__ epart,
    const float* __restrict__ bg2, const float* __restrict__ be2,
    float* __restrict__ out)
{
    const int b = blockIdx.x * 256 + threadIdx.x;
    float logit[8];
#pragma unroll
    for (int e = 0; e < 8; ++e) logit[e] = bg2[e];
    const float* gp = gpart + (size_t)b * 128;
#pragma unroll
    for (int cN = 0; cN < 16; ++cN)
#pragma unroll
        for (int e = 0; e < 8; ++e) logit[e] += gp[cN * 8 + e];

    float eo[8];
    const float* ep = epart + (size_t)b * E_DIM * NC;
#pragma unroll
    for (int e = 0; e < 8; ++e) {
        float s = be2[e];
#pragma unroll
        for (int cN = 0; cN < NC; ++cN) s += ep[e * NC + cN];
        eo[e] = s;
    }

    int i1 = 0; float m1 = logit[0];
#pragma unroll
    for (int e = 1; e < 8; ++e) if (logit[e] > m1) { m1 = logit[e]; i1 = e; }
    int i2 = -1; float m2 = -3.4e38f;
#pragma unroll
    for (int e = 0; e < 8; ++e) if (e != i1 && logit[e] > m2) { m2 = logit[e]; i2 = e; }

    const float w2 = expf(m2 - m1);
    out[b] = (eo[i1] + w2 * eo[i2]) / (1.f + w2);
}

// ---------------------------------------------------------------------------
extern "C" void kernel_launch(void* const* d_in, const int* in_sizes, int n_in,
                              void* d_out, int out_size, void* d_ws, size_t ws_size,
                              hipStream_t stream) {
    (void)in_sizes; (void)n_in; (void)out_size;
    const float* x   = (const float*)d_in[0];
    const float* We1 = (const float*)d_in[1];
    const float* be1 = (const float*)d_in[2];
    const float* We2 = (const float*)d_in[3];
    const float* be2 = (const float*)d_in[4];
    const float* Wg1 = (const float*)d_in[5];
    const float* bg1 = (const float*)d_in[6];
    const float* Wg2 = (const float*)d_in[7];
    const float* bg2 = (const float*)d_in[8];
    float* out = (float*)d_out;

    char* ws = (char*)d_ws;
    size_t off = 0;
    float* gpart = (float*)(ws + off);                 off += (size_t)B_DIM * 128 * 4;            // 8 MB
    float* epart = (float*)(ws + off);                 off += (size_t)B_DIM * 128 * 4;            // 8 MB
    unsigned short* panA = (unsigned short*)(ws + off); off += (size_t)B_DIM * H_DIM * 2;          // 128 MB
    unsigned short* panB = (unsigned short*)(ws + off); off += (size_t)E_DIM * H2_DIM * H_DIM * 2; // 128 MB
    const size_t NEED = off;

    if (ws_size >= NEED) {
        build_xA_panels<<<dim3(64, 64), 256, 0, stream>>>(x, panA);
        build_w1B_panels<<<dim3(32, 64, 8), 256, 0, stream>>>(We1, panB);
        moe_expert_gemm_256<<<4096, 512, 0, stream>>>(panA, panB, be1, We2, epart);
        moe_gate_gemm<<<dim3(16, 128), 256, 0, stream>>>(x, Wg1, bg1, Wg2, gpart);
        moe_finalize<8><<<64, 256, 0, stream>>>(gpart, epart, bg2, be2, out);
    } else {
        moe_expert_gemm<<<dim3(128, 128), 256, 0, stream>>>(x, We1, be1, We2, epart);
        moe_gate_gemm<<<dim3(16, 128), 256, 0, stream>>>(x, Wg1, bg1, Wg2, gpart);
        moe_finalize<16><<<64, 256, 0, stream>>>(gpart, epart, bg2, be2, out);
    }
}

// Round 7
// 3068.765 us; speedup vs baseline: 1.0904x; 1.0161x over previous
//
#include <hip/hip_runtime.h>
#include <hip/hip_bf16.h>
#include <stdint.h>

// MoE head. Expert path: prepasses build PRE-SWIZZLED bf16 staging panels
// (16 KB units = one global_load_lds stage, contiguous) for x and We1^T;
// 256x256 8-wave MFMA GEMM, 4 phases/K-tile with READ-AHEAD register
// pipelining: ds_reads for phase p+1 issue before phase p's barrier, MFMA
// consumes registers loaded one phase earlier -> LDS port drains under MFMA.
// Counted vmcnt(8) at ph0/ph2 only; 2-level (L3/L2) block mapping.
// Gate path: 3-term bf16 split GEMM (fp32-class accuracy for top-k).
// Finalize: reduce partials, top-2, renormalized softmax combine.

#define B_DIM  16384
#define H_DIM  4096
#define H2_DIM 2048
#define E_DIM  8

typedef __attribute__((ext_vector_type(8))) short short8;
typedef __attribute__((ext_vector_type(4))) float f32x4;

static __device__ __forceinline__ unsigned int bf16_rn(float f) {
    unsigned int u = __builtin_bit_cast(unsigned int, f);
    u += 0x7FFFu + ((u >> 16) & 1u);
    return u >> 16;
}
static __device__ __forceinline__ float bf16f(unsigned int h) {
    unsigned int u = h << 16;
    return __builtin_bit_cast(float, u);
}

static __device__ __forceinline__ void gload_lds16(const void* g, void* l) {
    __builtin_amdgcn_global_load_lds(
        (const __attribute__((address_space(1))) unsigned int*)g,
        (__attribute__((address_space(3))) unsigned int*)l,
        16, 0, 0);
}

// ---------------------------------------------------------------------------
// Prepass 1: x fp32 -> panel layout panA[bm(64)][t(64)][h(2)]{16KB unit}.
// Unit internal: [row(256)][slot(4)]{8 bf16}, stored slot = kslot ^ ((row>>1)&3)
// ---------------------------------------------------------------------------
__global__ __launch_bounds__(256) void build_xA_panels(
    const float* __restrict__ x, unsigned short* __restrict__ panA)
{
    const int t = blockIdx.x, bm = blockIdx.y, tid = threadIdx.x;
    const size_t ubase = (size_t)(bm * 64 + t) * 2 * 8192;   // elems (h=0)
#pragma unroll
    for (int u = 0; u < 8; ++u) {
        const int gid = u * 256 + tid;
        const int h = gid >> 10, rem = gid & 1023;
        const int row = rem >> 2, slot = rem & 3;
        const int kslot = slot ^ ((row >> 1) & 3);
        const float* s = x + (size_t)(bm * 256 + row) * H_DIM
                           + t * 64 + h * 32 + kslot * 8;
        f32x4 a = ((const f32x4*)s)[0], b = ((const f32x4*)s)[1];
        uint4 o;
        o.x = bf16_rn(a[0]) | (bf16_rn(a[1]) << 16);
        o.y = bf16_rn(a[2]) | (bf16_rn(a[3]) << 16);
        o.z = bf16_rn(b[0]) | (bf16_rn(b[1]) << 16);
        o.w = bf16_rn(b[2]) | (bf16_rn(b[3]) << 16);
        *(uint4*)(panA + ubase + (size_t)h * 8192 + row * 32 + slot * 8) = o;
    }
}

// ---------------------------------------------------------------------------
// Prepass 2: We1[e][k][d] fp32 -> panB[nbG(64)][t(64)][h(2)]{16KB unit},
// unit internal [col(256)][slot(4)]{8 bf16 along k}, same swizzle.
// LDS 64x64 tile transpose per (e, t, dblk).  dblk in [0,32) = H2/64.
// ---------------------------------------------------------------------------
__global__ __launch_bounds__(256) void build_w1B_panels(
    const float* __restrict__ We1, unsigned short* __restrict__ panB)
{
    __shared__ unsigned short tile[64][72];
    const int dblk = blockIdx.x, t = blockIdx.y, e = blockIdx.z;
    const int tid = threadIdx.x;
    {
        const int kr = tid >> 2, c0 = (tid & 3) * 16;
        const float* s = We1 + ((size_t)e * H_DIM + t * 64 + kr) * H2_DIM
                             + dblk * 64 + c0;
#pragma unroll
        for (int q = 0; q < 4; ++q) {
            f32x4 v = ((const f32x4*)s)[q];
            tile[kr][c0 + q * 4 + 0] = (unsigned short)bf16_rn(v[0]);
            tile[kr][c0 + q * 4 + 1] = (unsigned short)bf16_rn(v[1]);
            tile[kr][c0 + q * 4 + 2] = (unsigned short)bf16_rn(v[2]);
            tile[kr][c0 + q * 4 + 3] = (unsigned short)bf16_rn(v[3]);
        }
    }
    __syncthreads();
    const int nbG = e * 8 + (dblk >> 2);
    const int col = tid >> 2, slot = tid & 3;
    const int colg = (dblk & 3) * 64 + col;
    const int kslot = slot ^ ((colg >> 1) & 3);
#pragma unroll
    for (int hh = 0; hh < 2; ++hh) {
        const int kl = hh * 32 + kslot * 8;
        uint4 o;
        o.x = (unsigned int)tile[kl + 0][col] | ((unsigned int)tile[kl + 1][col] << 16);
        o.y = (unsigned int)tile[kl + 2][col] | ((unsigned int)tile[kl + 3][col] << 16);
        o.z = (unsigned int)tile[kl + 4][col] | ((unsigned int)tile[kl + 5][col] << 16);
        o.w = (unsigned int)tile[kl + 6][col] | ((unsigned int)tile[kl + 7][col] << 16);
        *(uint4*)(panB + (((size_t)nbG * 64 + t) * 2 + hh) * 8192
                        + colg * 32 + slot * 8) = o;
    }
}

// ---------------------------------------------------------------------------
// Expert GEMM: 256x256 tile, BK=64, 8 waves, read-ahead pipelined phases.
// epart[b][e][chunk8] = sum_{d in 256-chunk} relu(x@We1 + be1) * We2
// ---------------------------------------------------------------------------
__global__ __launch_bounds__(512, 2) void moe_expert_gemm_256(
    const unsigned short* __restrict__ panA, const unsigned short* __restrict__ panB,
    const float* __restrict__ be1, const float* __restrict__ We2,
    float* __restrict__ epart)
{
    __shared__ short lA[2][2][8192];   // 64 KB  [dbuf][k-half][256r x 32k]
    __shared__ short lB[2][2][8192];   // 64 KB
    __shared__ float red[4][256];      // 4 KB

    const int tid  = threadIdx.x;
    const int lane = tid & 63;
    const int wv   = tid >> 6;   // 0..7
    const int wm   = wv >> 2;    // 0..1
    const int wn   = wv & 3;     // 0..3

    // 2-level temporal tiling (bijective): batch = 256 blocks = 16bm x 16nb
    const int lin = blockIdx.x;
    const int sb  = lin >> 8, i5 = lin & 255;
    const int sbm = sb & 3, snb = sb >> 2;
    const int xcd = i5 & 7, j5 = i5 >> 3;
    const int bm  = sbm * 16 + (xcd & 1) * 8 + (j5 & 7);
    const int nb  = snb * 16 + (xcd >> 1) * 4 + (j5 >> 3);
    const int e = nb >> 3, chunk = nb & 7;
    const int dbase = chunk * 256;

    const char* Abase = (const char*)panA + ((size_t)bm << 21);
    const char* Bbase = (const char*)panB + ((size_t)nb << 21);

#define STAGE_U(ARR, GB, TT, HH, CC) do {                                      \
    const char* u_ = GB + (((size_t)(TT) * 2 + (HH)) << 14);                   \
    gload_lds16(u_ + tid * 16, (char*)&ARR[CC][HH][0] + wv * 1024);            \
    gload_lds16(u_ + 8192 + tid * 16, (char*)&ARR[CC][HH][0] + 8192 + wv * 1024); \
} while (0)

#define RD8(BASE, OFF) \
    (*reinterpret_cast<const short8*>(reinterpret_cast<const char*>(BASE) + (OFF)))

    // fragment read bases: row r, global kslot = lane>>4,
    // stored slot = (lane>>4) ^ ((r>>1)&3)  (matches panel swizzle)
    const int rA = wm * 128 + (lane & 15);
    const int offA = rA * 64 + ((((lane >> 4)) ^ ((rA >> 1) & 3)) << 4);
    const int rB = wn * 64 + (lane & 15);
    const int offB = rB * 64 + ((((lane >> 4)) ^ ((rB >> 1) & 3)) << 4);

    f32x4 acc[8][4];
#pragma unroll
    for (int i = 0; i < 8; ++i)
#pragma unroll
        for (int j = 0; j < 4; ++j) acc[i][j] = (f32x4){0.f, 0.f, 0.f, 0.f};

    short8 aE[4], aO[4], bK0[4], bK1[4];   // register frag banks

    // prologue: stage h0(0), h1(0), h0(1); wait h0(0); pre-read ph0 operands
    STAGE_U(lA, Abase, 0, 0, 0);
    STAGE_U(lB, Bbase, 0, 0, 0);
    STAGE_U(lA, Abase, 0, 1, 0);
    STAGE_U(lB, Bbase, 0, 1, 0);
    STAGE_U(lA, Abase, 1, 0, 1);
    STAGE_U(lB, Bbase, 1, 0, 1);
    asm volatile("s_waitcnt vmcnt(8)");
    __builtin_amdgcn_s_barrier();
#pragma unroll
    for (int n = 0; n < 4; ++n) bK0[n] = RD8(&lB[0][0][0], offB + n * 1024);
#pragma unroll
    for (int i = 0; i < 4; ++i) aE[i] = RD8(&lA[0][0][0], offA + i * 1024);

// One tile (64 K), c = dbuf literal. Phases:
//  ph0: stage h1(tn1)->c^1, vmcnt(8) [h1(t) ready], read aO(k0); MFMA mi0-3 k0
//  ph1: read aE(k1), bK1;                                MFMA mi4-7 k0
//  ph2: stage h0(tn2)->c, vmcnt(8) [h0(t+1) ready], read aO(k1); MFMA mi0-3 k1
//  ph3: read next-tile aE(k0), bK0 from [c^1][0];        MFMA mi4-7 k1
#define TILE(c, tn1, tn2) do {                                                 \
    STAGE_U(lA, Abase, tn1, 1, (c) ^ 1);                                       \
    STAGE_U(lB, Bbase, tn1, 1, (c) ^ 1);                                       \
    asm volatile("s_waitcnt vmcnt(8)");                                        \
    _Pragma("unroll")                                                          \
    for (int i = 0; i < 4; ++i)                                                \
        aO[i] = RD8(&lA[c][0][0], offA + (4 + i) * 1024);                      \
    __builtin_amdgcn_s_barrier();                                              \
    __builtin_amdgcn_s_setprio(1);                                             \
    _Pragma("unroll")                                                          \
    for (int i = 0; i < 4; ++i)                                                \
        _Pragma("unroll")                                                      \
        for (int n = 0; n < 4; ++n)                                            \
            acc[i][n] = __builtin_amdgcn_mfma_f32_16x16x32_bf16(aE[i], bK0[n], acc[i][n], 0, 0, 0); \
    __builtin_amdgcn_s_setprio(0);                                             \
    __builtin_amdgcn_s_barrier();                                              \
    _Pragma("unroll")                                                          \
    for (int i = 0; i < 4; ++i)                                                \
        aE[i] = RD8(&lA[c][1][0], offA + i * 1024);                            \
    _Pragma("unroll")                                                          \
    for (int n = 0; n < 4; ++n)                                                \
        bK1[n] = RD8(&lB[c][1][0], offB + n * 1024);                           \
    __builtin_amdgcn_s_barrier();                                              \
    __builtin_amdgcn_s_setprio(1);                                             \
    _Pragma("unroll")                                                          \
    for (int i = 0; i < 4; ++i)                                                \
        _Pragma("unroll")                                                      \
        for (int n = 0; n < 4; ++n)                                            \
            acc[4 + i][n] = __builtin_amdgcn_mfma_f32_16x16x32_bf16(aO[i], bK0[n], acc[4 + i][n], 0, 0, 0); \
    __builtin_amdgcn_s_setprio(0);                                             \
    __builtin_amdgcn_s_barrier();                                              \
    STAGE_U(lA, Abase, tn2, 0, c);                                             \
    STAGE_U(lB, Bbase, tn2, 0, c);                                             \
    asm volatile("s_waitcnt vmcnt(8)");                                        \
    _Pragma("unroll")                                                          \
    for (int i = 0; i < 4; ++i)                                                \
        aO[i] = RD8(&lA[c][1][0], offA + (4 + i) * 1024);                      \
    __builtin_amdgcn_s_barrier();                                              \
    __builtin_amdgcn_s_setprio(1);                                             \
    _Pragma("unroll")                                                          \
    for (int i = 0; i < 4; ++i)                                                \
        _Pragma("unroll")                                                      \
        for (int n = 0; n < 4; ++n)                                            \
            acc[i][n] = __builtin_amdgcn_mfma_f32_16x16x32_bf16(aE[i], bK1[n], acc[i][n], 0, 0, 0); \
    __builtin_amdgcn_s_setprio(0);                                             \
    __builtin_amdgcn_s_barrier();                                              \
    _Pragma("unroll")                                                          \
    for (int i = 0; i < 4; ++i)                                                \
        aE[i] = RD8(&lA[(c) ^ 1][0][0], offA + i * 1024);                      \
    _Pragma("unroll")                                                          \
    for (int n = 0; n < 4; ++n)                                                \
        bK0[n] = RD8(&lB[(c) ^ 1][0][0], offB + n * 1024);                     \
    __builtin_amdgcn_s_barrier();                                              \
    __builtin_amdgcn_s_setprio(1);                                             \
    _Pragma("unroll")                                                          \
    for (int i = 0; i < 4; ++i)                                                \
        _Pragma("unroll")                                                      \
        for (int n = 0; n < 4; ++n)                                            \
            acc[4 + i][n] = __builtin_amdgcn_mfma_f32_16x16x32_bf16(aO[i], bK1[n], acc[4 + i][n], 0, 0, 0); \
    __builtin_amdgcn_s_setprio(0);                                             \
    __builtin_amdgcn_s_barrier();                                              \
} while (0)

    for (int t = 0; t < 64; t += 2) {
        const int tn2a = (t + 2 < 64) ? t + 2 : 63;
        const int tn3b = (t + 3 < 64) ? t + 3 : 63;
        TILE(0, t + 1, tn2a);
        TILE(1, tn2a, tn3b);
    }
#undef TILE
#undef STAGE_U

    // epilogue: relu(acc + be1) * We2, reduce over this wave's 64 d-cols
    const int cc = lane & 15, g = lane >> 4;
    float w2v[4], b1v[4];
#pragma unroll
    for (int ni = 0; ni < 4; ++ni) {
        const int d = dbase + wn * 64 + ni * 16 + cc;
        b1v[ni] = be1[e * H2_DIM + d];
        w2v[ni] = We2[e * H2_DIM + d];
    }
#pragma unroll
    for (int mi = 0; mi < 8; ++mi) {
#pragma unroll
        for (int r = 0; r < 4; ++r) {
            float s = 0.f;
#pragma unroll
            for (int ni = 0; ni < 4; ++ni) {
                float v = acc[mi][ni][r] + b1v[ni];
                v = fmaxf(v, 0.f);
                s = fmaf(v, w2v[ni], s);
            }
            s += __shfl_xor(s, 1);
            s += __shfl_xor(s, 2);
            s += __shfl_xor(s, 4);
            s += __shfl_xor(s, 8);
            if (cc == 0) red[wn][wm * 128 + mi * 16 + g * 4 + r] = s;
        }
    }
    __syncthreads();
    if (tid < 256) {
        const int b = bm * 256 + tid;
        epart[((size_t)b * E_DIM + e) * 8 + chunk] =
            red[0][tid] + red[1][tid] + red[2][tid] + red[3][tid];
    }
}

// ---------------------------------------------------------------------------
// Expert GEMM (fallback, fp32 in-kernel conversion) — round-1 verified.
// Writes epart [b][e][16].
// ---------------------------------------------------------------------------
__global__ __launch_bounds__(256, 2) void moe_expert_gemm(
    const float* __restrict__ x, const float* __restrict__ We1,
    const float* __restrict__ be1, const float* __restrict__ We2,
    float* __restrict__ epart)
{
    __shared__ short lA[128 * 64];
    __shared__ short lB[128 * 64];
    __shared__ float red[2][128];

    const int tid  = threadIdx.x;
    const int lane = tid & 63;
    const int wm   = (tid >> 6) >> 1;
    const int wn   = (tid >> 6) & 1;
    const int nb = blockIdx.x, bm = blockIdx.y;
    const int e = nb >> 4, chunk = nb & 15;
    const int dbase = chunk * 128;

    const float* Asrc = x + (size_t)bm * 128 * H_DIM;
    const float* Bsrc = We1 + (size_t)e * H_DIM * H2_DIM + dbase;

    f32x4 acc[4][4];
#pragma unroll
    for (int i = 0; i < 4; ++i)
#pragma unroll
        for (int j = 0; j < 4; ++j) acc[i][j] = (f32x4){0.f, 0.f, 0.f, 0.f};

    const int arow0 = tid >> 4, af4 = tid & 15;
    const int bn = tid & 127, bkc0 = tid >> 7;

    for (int k0 = 0; k0 < H_DIM; k0 += 64) {
        __syncthreads();
#pragma unroll
        for (int j = 0; j < 8; ++j) {
            const int row = arow0 + j * 16;
            const float* p = Asrc + (size_t)row * H_DIM + k0 + af4 * 4;
            float a0 = p[0], a1 = p[1], a2 = p[2], a3 = p[3];
            uint2 wv2;
            wv2.x = bf16_rn(a0) | (bf16_rn(a1) << 16);
            wv2.y = bf16_rn(a2) | (bf16_rn(a3) << 16);
            const int byte = row * 128 + ((af4 * 8) ^ ((row & 7) << 4));
            *reinterpret_cast<uint2*>(reinterpret_cast<char*>(lA) + byte) = wv2;
        }
#pragma unroll
        for (int j = 0; j < 4; ++j) {
            const int kc = bkc0 + 2 * j;
            const float* p = Bsrc + (size_t)(k0 + kc * 8) * H2_DIM + bn;
            uint4 wv4;
            wv4.x = bf16_rn(p[0])          | (bf16_rn(p[H2_DIM])     << 16);
            wv4.y = bf16_rn(p[2 * H2_DIM]) | (bf16_rn(p[3 * H2_DIM]) << 16);
            wv4.z = bf16_rn(p[4 * H2_DIM]) | (bf16_rn(p[5 * H2_DIM]) << 16);
            wv4.w = bf16_rn(p[6 * H2_DIM]) | (bf16_rn(p[7 * H2_DIM]) << 16);
            const int byte = bn * 128 + ((kc * 16) ^ ((bn & 7) << 4));
            *reinterpret_cast<uint4*>(reinterpret_cast<char*>(lB) + byte) = wv4;
        }
        __syncthreads();
#pragma unroll
        for (int kk = 0; kk < 2; ++kk) {
            const int kbyte = kk * 64 + ((lane >> 4) << 4);
            short8 af[4], bfr[4];
#pragma unroll
            for (int mi = 0; mi < 4; ++mi) {
                const int r = wm * 64 + mi * 16 + (lane & 15);
                af[mi] = *reinterpret_cast<const short8*>(
                    reinterpret_cast<const char*>(lA) + r * 128 + (kbyte ^ ((r & 7) << 4)));
            }
#pragma unroll
            for (int ni = 0; ni < 4; ++ni) {
                const int r = wn * 64 + ni * 16 + (lane & 15);
                bfr[ni] = *reinterpret_cast<const short8*>(
                    reinterpret_cast<const char*>(lB) + r * 128 + (kbyte ^ ((r & 7) << 4)));
            }
#pragma unroll
            for (int mi = 0; mi < 4; ++mi)
#pragma unroll
                for (int ni = 0; ni < 4; ++ni)
                    acc[mi][ni] = __builtin_amdgcn_mfma_f32_16x16x32_bf16(
                        af[mi], bfr[ni], acc[mi][ni], 0, 0, 0);
        }
    }

    const int c = lane & 15, g = lane >> 4;
    float w2v[4], b1v[4];
#pragma unroll
    for (int ni = 0; ni < 4; ++ni) {
        const int d = dbase + wn * 64 + ni * 16 + c;
        b1v[ni] = be1[e * H2_DIM + d];
        w2v[ni] = We2[e * H2_DIM + d];
    }
#pragma unroll
    for (int mi = 0; mi < 4; ++mi) {
#pragma unroll
        for (int r = 0; r < 4; ++r) {
            float s = 0.f;
#pragma unroll
            for (int ni = 0; ni < 4; ++ni) {
                float v = acc[mi][ni][r] + b1v[ni];
                v = fmaxf(v, 0.f);
                s = fmaf(v, w2v[ni], s);
            }
            s += __shfl_xor(s, 1);
            s += __shfl_xor(s, 2);
            s += __shfl_xor(s, 4);
            s += __shfl_xor(s, 8);
            if (c == 0) red[wn][wm * 64 + mi * 16 + g * 4 + r] = s;
        }
    }
    __syncthreads();
    if (tid < 128) {
        const int b = bm * 128 + tid;
        epart[((size_t)b * E_DIM + e) * 16 + chunk] = red[0][tid] + red[1][tid];
    }
}

// ---------------------------------------------------------------------------
// Gate GEMM, 3-term bf16 split for ~fp32 accuracy (top-k must match ref).
// ---------------------------------------------------------------------------
__global__ __launch_bounds__(256, 2) void moe_gate_gemm(
    const float* __restrict__ x, const float* __restrict__ Wg1,
    const float* __restrict__ bg1, const float* __restrict__ Wg2,
    float* __restrict__ gpart)
{
    __shared__ short lAh[128 * 64], lAl[128 * 64];
    __shared__ short lBh[128 * 64], lBl[128 * 64];
    __shared__ float lW2[128 * 8];
    __shared__ float gred[2][128][8];

    const int tid  = threadIdx.x;
    const int lane = tid & 63;
    const int wm = (tid >> 6) >> 1, wn = (tid >> 6) & 1;
    const int nb = blockIdx.x, bm = blockIdx.y;
    const int dbase = nb * 128;

    const float* Asrc = x + (size_t)bm * 128 * H_DIM;
    const float* Bsrc = Wg1 + dbase;

    {
        const f32x4* s = reinterpret_cast<const f32x4*>(Wg2 + (size_t)dbase * 8);
        reinterpret_cast<f32x4*>(lW2)[tid] = s[tid];
    }

    f32x4 acc[4][4];
#pragma unroll
    for (int i = 0; i < 4; ++i)
#pragma unroll
        for (int j = 0; j < 4; ++j) acc[i][j] = (f32x4){0.f, 0.f, 0.f, 0.f};

    const int arow0 = tid >> 4, af4 = tid & 15;
    const int bn = tid & 127, bkc0 = tid >> 7;

    for (int k0 = 0; k0 < H_DIM; k0 += 64) {
        __syncthreads();
#pragma unroll
        for (int j = 0; j < 8; ++j) {
            const int row = arow0 + j * 16;
            const float* p = Asrc + (size_t)row * H_DIM + k0 + af4 * 4;
            float a[4] = {p[0], p[1], p[2], p[3]};
            unsigned int hb[4], lb[4];
#pragma unroll
            for (int q = 0; q < 4; ++q) {
                hb[q] = bf16_rn(a[q]);
                lb[q] = bf16_rn(a[q] - bf16f(hb[q]));
            }
            const int byte = row * 128 + ((af4 * 8) ^ ((row & 7) << 4));
            *reinterpret_cast<uint2*>(reinterpret_cast<char*>(lAh) + byte) =
                make_uint2(hb[0] | (hb[1] << 16), hb[2] | (hb[3] << 16));
            *reinterpret_cast<uint2*>(reinterpret_cast<char*>(lAl) + byte) =
                make_uint2(lb[0] | (lb[1] << 16), lb[2] | (lb[3] << 16));
        }
#pragma unroll
        for (int j = 0; j < 4; ++j) {
            const int kc = bkc0 + 2 * j;
            const float* p = Bsrc + (size_t)(k0 + kc * 8) * H2_DIM + bn;
            unsigned int hb[8], lb[8];
#pragma unroll
            for (int q = 0; q < 8; ++q) {
                float v = p[(size_t)q * H2_DIM];
                hb[q] = bf16_rn(v);
                lb[q] = bf16_rn(v - bf16f(hb[q]));
            }
            const int byte = bn * 128 + ((kc * 16) ^ ((bn & 7) << 4));
            *reinterpret_cast<uint4*>(reinterpret_cast<char*>(lBh) + byte) =
                make_uint4(hb[0] | (hb[1] << 16), hb[2] | (hb[3] << 16),
                           hb[4] | (hb[5] << 16), hb[6] | (hb[7] << 16));
            *reinterpret_cast<uint4*>(reinterpret_cast<char*>(lBl) + byte) =
                make_uint4(lb[0] | (lb[1] << 16), lb[2] | (lb[3] << 16),
                           lb[4] | (lb[5] << 16), lb[6] | (lb[7] << 16));
        }
        __syncthreads();
#pragma unroll
        for (int kk = 0; kk < 2; ++kk) {
            const int kbyte = kk * 64 + ((lane >> 4) << 4);
            short8 ah[4], al[4], bh[4], bl[4];
#pragma unroll
            for (int mi = 0; mi < 4; ++mi) {
                const int r = wm * 64 + mi * 16 + (lane & 15);
                const int off = r * 128 + (kbyte ^ ((r & 7) << 4));
                ah[mi] = *reinterpret_cast<const short8*>(reinterpret_cast<const char*>(lAh) + off);
                al[mi] = *reinterpret_cast<const short8*>(reinterpret_cast<const char*>(lAl) + off);
            }
#pragma unroll
            for (int ni = 0; ni < 4; ++ni) {
                const int r = wn * 64 + ni * 16 + (lane & 15);
                const int off = r * 128 + (kbyte ^ ((r & 7) << 4));
                bh[ni] = *reinterpret_cast<const short8*>(reinterpret_cast<const char*>(lBh) + off);
                bl[ni] = *reinterpret_cast<const short8*>(reinterpret_cast<const char*>(lBl) + off);
            }
#pragma unroll
            for (int mi = 0; mi < 4; ++mi)
#pragma unroll
                for (int ni = 0; ni < 4; ++ni) {
                    acc[mi][ni] = __builtin_amdgcn_mfma_f32_16x16x32_bf16(ah[mi], bh[ni], acc[mi][ni], 0, 0, 0);
                    acc[mi][ni] = __builtin_amdgcn_mfma_f32_16x16x32_bf16(ah[mi], bl[ni], acc[mi][ni], 0, 0, 0);
                    acc[mi][ni] = __builtin_amdgcn_mfma_f32_16x16x32_bf16(al[mi], bh[ni], acc[mi][ni], 0, 0, 0);
                }
        }
    }

    const int c = lane & 15, g = lane >> 4;
    float bgv[4];
#pragma unroll
    for (int ni = 0; ni < 4; ++ni) bgv[ni] = bg1[dbase + wn * 64 + ni * 16 + c];
#pragma unroll
    for (int mi = 0; mi < 4; ++mi) {
#pragma unroll
        for (int r = 0; r < 4; ++r) {
            float gv[4];
#pragma unroll
            for (int ni = 0; ni < 4; ++ni)
                gv[ni] = fmaxf(acc[mi][ni][r] + bgv[ni], 0.f);
#pragma unroll
            for (int e8 = 0; e8 < 8; ++e8) {
                float t = 0.f;
#pragma unroll
                for (int ni = 0; ni < 4; ++ni)
                    t = fmaf(gv[ni], lW2[(wn * 64 + ni * 16 + c) * 8 + e8], t);
                t += __shfl_xor(t, 1);
                t += __shfl_xor(t, 2);
                t += __shfl_xor(t, 4);
                t += __shfl_xor(t, 8);
                if (c == e8) gred[wn][wm * 64 + mi * 16 + g * 4 + r][e8] = t;
            }
        }
    }
    __syncthreads();
    {
        const int row = tid & 127;
        const int ebase = (tid >> 7) * 4;
        const int b = bm * 128 + row;
#pragma unroll
        for (int i = 0; i < 4; ++i) {
            const int e8 = ebase + i;
            gpart[(size_t)b * 128 + nb * 8 + e8] = gred[0][row][e8] + gred[1][row][e8];
        }
    }
}

// ---------------------------------------------------------------------------
// Finalize: reduce partials, softmax top-2 (renormalized), combine.
// ---------------------------------------------------------------------------
template <int NC>
__global__ __launch_bounds__(256) void moe_finalize(
    const float* __restrict__ gpart, const float* __restrict__ epart,
    const float* __restrict__ bg2, const float* __restrict__ be2,
    float* __restrict__ out)
{
    const int b = blockIdx.x * 256 + threadIdx.x;
    float logit[8];
#pragma unroll
    for (int e = 0; e < 8; ++e) logit[e] = bg2[e];
    const float* gp = gpart + (size_t)b * 128;
#pragma unroll
    for (int cN = 0; cN < 16; ++cN)
#pragma unroll
        for (int e = 0; e < 8; ++e) logit[e] += gp[cN * 8 + e];

    float eo[8];
    const float* ep = epart + (size_t)b * E_DIM * NC;
#pragma unroll
    for (int e = 0; e < 8; ++e) {
        float s = be2[e];
#pragma unroll
        for (int cN = 0; cN < NC; ++cN) s += ep[e * NC + cN];
        eo[e] = s;
    }

    int i1 = 0; float m1 = logit[0];
#pragma unroll
    for (int e = 1; e < 8; ++e) if (logit[e] > m1) { m1 = logit[e]; i1 = e; }
    int i2 = -1; float m2 = -3.4e38f;
#pragma unroll
    for (int e = 0; e < 8; ++e) if (e != i1 && logit[e] > m2) { m2 = logit[e]; i2 = e; }

    const float w2 = expf(m2 - m1);
    out[b] = (eo[i1] + w2 * eo[i2]) / (1.f + w2);
}

// ---------------------------------------------------------------------------
extern "C" void kernel_launch(void* const* d_in, const int* in_sizes, int n_in,
                              void* d_out, int out_size, void* d_ws, size_t ws_size,
                              hipStream_t stream) {
    (void)in_sizes; (void)n_in; (void)out_size;
    const float* x   = (const float*)d_in[0];
    const float* We1 = (const float*)d_in[1];
    const float* be1 = (const float*)d_in[2];
    const float* We2 = (const float*)d_in[3];
    const float* be2 = (const float*)d_in[4];
    const float* Wg1 = (const float*)d_in[5];
    const float* bg1 = (const float*)d_in[6];
    const float* Wg2 = (const float*)d_in[7];
    const float* bg2 = (const float*)d_in[8];
    float* out = (float*)d_out;

    char* ws = (char*)d_ws;
    size_t off = 0;
    float* gpart = (float*)(ws + off);                 off += (size_t)B_DIM * 128 * 4;            // 8 MB
    float* epart = (float*)(ws + off);                 off += (size_t)B_DIM * 128 * 4;            // 8 MB
    unsigned short* panA = (unsigned short*)(ws + off); off += (size_t)B_DIM * H_DIM * 2;          // 128 MB
    unsigned short* panB = (unsigned short*)(ws + off); off += (size_t)E_DIM * H2_DIM * H_DIM * 2; // 128 MB
    const size_t NEED = off;

    if (ws_size >= NEED) {
        build_xA_panels<<<dim3(64, 64), 256, 0, stream>>>(x, panA);
        build_w1B_panels<<<dim3(32, 64, 8), 256, 0, stream>>>(We1, panB);
        moe_expert_gemm_256<<<4096, 512, 0, stream>>>(panA, panB, be1, We2, epart);
        moe_gate_gemm<<<dim3(16, 128), 256, 0, stream>>>(x, Wg1, bg1, Wg2, gpart);
        moe_finalize<8><<<64, 256, 0, stream>>>(gpart, epart, bg2, be2, out);
    } else {
        moe_expert_gemm<<<dim3(128, 128), 256, 0, stream>>>(x, We1, be1, We2, epart);
        moe_gate_gemm<<<dim3(16, 128), 256, 0, stream>>>(x, Wg1, bg1, Wg2, gpart);
        moe_finalize<16><<<64, 256, 0, stream>>>(gpart, epart, bg2, be2, out);
    }
}

// Round 9
// 2987.385 us; speedup vs baseline: 1.1201x; 1.0272x over previous
//
#include <hip/hip_runtime.h>
#include <hip/hip_bf16.h>
#include <stdint.h>

// MoE head. Expert path: prepasses build PRE-SWIZZLED bf16 staging panels
// for x and We1^T (16KB units); expert GEMM for TLP: 128x256 tile, BK=32,
// 8 waves of 64x64, LDS 50KB, launch_bounds(512,4) -> 2 blocks/CU.
// Per K-tile (catalog 2-phase recipe): STAGE(next->c^1) 3x global_load_lds,
// ds_read(c), 16 MFMA, vmcnt(0), ONE s_barrier. Cross-block overlap hides
// the drain (m97/m114 mechanism).
// R9 fixes vs R8: (a) A-stage source = ua_+tid*16 / dest wv*1024 (R8's
// tid>>1 duplicated chunks across lane-indexed LDS dests -> garbage A);
// (b) vmcnt(0) before the barrier (R8's post-MFMA vmcnt(3) was a no-op and
// left a RAW race on the next iteration's ds_reads).
// Gate path: 3-term bf16 split GEMM (fp32-class accuracy for top-k).
// Finalize: reduce partials, top-2, renormalized softmax combine.

#define B_DIM  16384
#define H_DIM  4096
#define H2_DIM 2048
#define E_DIM  8

typedef __attribute__((ext_vector_type(8))) short short8;
typedef __attribute__((ext_vector_type(4))) float f32x4;

static __device__ __forceinline__ unsigned int bf16_rn(float f) {
    unsigned int u = __builtin_bit_cast(unsigned int, f);
    u += 0x7FFFu + ((u >> 16) & 1u);
    return u >> 16;
}
static __device__ __forceinline__ float bf16f(unsigned int h) {
    unsigned int u = h << 16;
    return __builtin_bit_cast(float, u);
}

static __device__ __forceinline__ void gload_lds16(const void* g, void* l) {
    __builtin_amdgcn_global_load_lds(
        (const __attribute__((address_space(1))) unsigned int*)g,
        (__attribute__((address_space(3))) unsigned int*)l,
        16, 0, 0);
}

// ---------------------------------------------------------------------------
// Prepass 1: x fp32 -> panel layout panA[bm256(64)][t(64)][h(2)]{16KB unit}.
// Unit internal: [row(256)][slot(4)]{8 bf16}, stored slot = kslot ^ ((row>>1)&3)
// (rows outer => a 128-row half-tile is a contiguous 8KB half of the unit).
// ---------------------------------------------------------------------------
__global__ __launch_bounds__(256) void build_xA_panels(
    const float* __restrict__ x, unsigned short* __restrict__ panA)
{
    const int t = blockIdx.x, bm = blockIdx.y, tid = threadIdx.x;
    const size_t ubase = (size_t)(bm * 64 + t) * 2 * 8192;   // elems (h=0)
#pragma unroll
    for (int u = 0; u < 8; ++u) {
        const int gid = u * 256 + tid;
        const int h = gid >> 10, rem = gid & 1023;
        const int row = rem >> 2, slot = rem & 3;
        const int kslot = slot ^ ((row >> 1) & 3);
        const float* s = x + (size_t)(bm * 256 + row) * H_DIM
                           + t * 64 + h * 32 + kslot * 8;
        f32x4 a = ((const f32x4*)s)[0], b = ((const f32x4*)s)[1];
        uint4 o;
        o.x = bf16_rn(a[0]) | (bf16_rn(a[1]) << 16);
        o.y = bf16_rn(a[2]) | (bf16_rn(a[3]) << 16);
        o.z = bf16_rn(b[0]) | (bf16_rn(b[1]) << 16);
        o.w = bf16_rn(b[2]) | (bf16_rn(b[3]) << 16);
        *(uint4*)(panA + ubase + (size_t)h * 8192 + row * 32 + slot * 8) = o;
    }
}

// ---------------------------------------------------------------------------
// Prepass 2: We1[e][k][d] fp32 -> panB[nbG(64)][t(64)][h(2)]{16KB unit},
// unit internal [col(256)][slot(4)]{8 bf16 along k}, same swizzle.
// LDS 64x64 tile transpose per (e, t, dblk).  dblk in [0,32) = H2/64.
// ---------------------------------------------------------------------------
__global__ __launch_bounds__(256) void build_w1B_panels(
    const float* __restrict__ We1, unsigned short* __restrict__ panB)
{
    __shared__ unsigned short tile[64][72];
    const int dblk = blockIdx.x, t = blockIdx.y, e = blockIdx.z;
    const int tid = threadIdx.x;
    {
        const int kr = tid >> 2, c0 = (tid & 3) * 16;
        const float* s = We1 + ((size_t)e * H_DIM + t * 64 + kr) * H2_DIM
                             + dblk * 64 + c0;
#pragma unroll
        for (int q = 0; q < 4; ++q) {
            f32x4 v = ((const f32x4*)s)[q];
            tile[kr][c0 + q * 4 + 0] = (unsigned short)bf16_rn(v[0]);
            tile[kr][c0 + q * 4 + 1] = (unsigned short)bf16_rn(v[1]);
            tile[kr][c0 + q * 4 + 2] = (unsigned short)bf16_rn(v[2]);
            tile[kr][c0 + q * 4 + 3] = (unsigned short)bf16_rn(v[3]);
        }
    }
    __syncthreads();
    const int nbG = e * 8 + (dblk >> 2);
    const int col = tid >> 2, slot = tid & 3;
    const int colg = (dblk & 3) * 64 + col;
    const int kslot = slot ^ ((colg >> 1) & 3);
#pragma unroll
    for (int hh = 0; hh < 2; ++hh) {
        const int kl = hh * 32 + kslot * 8;
        uint4 o;
        o.x = (unsigned int)tile[kl + 0][col] | ((unsigned int)tile[kl + 1][col] << 16);
        o.y = (unsigned int)tile[kl + 2][col] | ((unsigned int)tile[kl + 3][col] << 16);
        o.z = (unsigned int)tile[kl + 4][col] | ((unsigned int)tile[kl + 5][col] << 16);
        o.w = (unsigned int)tile[kl + 6][col] | ((unsigned int)tile[kl + 7][col] << 16);
        *(uint4*)(panB + (((size_t)nbG * 64 + t) * 2 + hh) * 8192
                        + colg * 32 + slot * 8) = o;
    }
}

// ---------------------------------------------------------------------------
// Expert GEMM: 128x256 tile, BK=32, 8 waves (2M x 4N) of 64x64 output.
// 2 blocks/CU (VGPR<=128, LDS 50KB). One barrier + one vmcnt(0) per K-tile.
// epart[b][e][chunk8] = sum_{d in 256-chunk} relu(x@We1 + be1) * We2
// ---------------------------------------------------------------------------
__global__ __launch_bounds__(512, 4) void moe_expert_gemm_128(
    const unsigned short* __restrict__ panA, const unsigned short* __restrict__ panB,
    const float* __restrict__ be1, const float* __restrict__ We2,
    float* __restrict__ epart)
{
    __shared__ short lA[2][4096];    // 2 x 8KB   [dbuf][128r x 32k]
    __shared__ short lB[2][8192];    // 2 x 16KB  [dbuf][256c x 32k]
    __shared__ float red[4][128];    // 2KB

    const int tid  = threadIdx.x;
    const int lane = tid & 63;
    const int wv   = tid >> 6;   // 0..7
    const int wm   = wv >> 2;    // 0..1
    const int wn   = wv & 3;     // 0..3

    // 2-level tiling (bijective over 8192): 32 batches of 16bm x 16nb;
    // within batch each XCD owns an 8bm x 4nb sub-tile.
    const int lin = blockIdx.x;
    const int sb  = lin >> 8, i5 = lin & 255;
    const int sbm = sb & 7, snb = sb >> 3;
    const int xcd = i5 & 7, j5 = i5 >> 3;
    const int bm  = sbm * 16 + (xcd & 1) * 8 + (j5 & 7);    // 0..127
    const int nb  = snb * 16 + (xcd >> 1) * 4 + (j5 >> 3);  // 0..63
    const int e = nb >> 3, chunk = nb & 7;
    const int dbase = chunk * 256;

    // A: 128-row half (8KB) of the 256-row panel unit; unit stride 16KB.
    const char* Abase = (const char*)panA + ((size_t)(bm >> 1) << 21)
                                          + ((size_t)(bm & 1) << 13);
    const char* Bbase = (const char*)panB + ((size_t)nb << 21);

    // 3 gloads/thread per K-tile: A 8KB (1) + B 16KB (2); linear LDS dest.
    // Each thread copies exactly its own 16B chunk (tid*16 -> wave base wv*1024
    // + lane*16). 512 threads x 16B = 8KB per gload round.
#define STAGE(TT, CC) do {                                                     \
    const char* ua_ = Abase + ((size_t)(TT) << 14);                            \
    gload_lds16(ua_ + tid * 16, (char*)&lA[CC][0] + wv * 1024);                \
    const char* ub_ = Bbase + ((size_t)(TT) << 14);                            \
    gload_lds16(ub_ + tid * 16, (char*)&lB[CC][0] + wv * 1024);                \
    gload_lds16(ub_ + 8192 + tid * 16, (char*)&lB[CC][0] + 8192 + wv * 1024);  \
} while (0)

#define RD8(BASE, OFF) \
    (*reinterpret_cast<const short8*>(reinterpret_cast<const char*>(BASE) + (OFF)))

    // fragment read bases (swizzle: stored slot = kslot ^ ((row>>1)&3))
    const int rA = wm * 64 + (lane & 15);
    const int offA = rA * 64 + ((((lane >> 4)) ^ ((rA >> 1) & 3)) << 4);
    const int rB = wn * 64 + (lane & 15);
    const int offB = rB * 64 + ((((lane >> 4)) ^ ((rB >> 1) & 3)) << 4);

    f32x4 acc[4][4];
#pragma unroll
    for (int i = 0; i < 4; ++i)
#pragma unroll
        for (int j = 0; j < 4; ++j) acc[i][j] = (f32x4){0.f, 0.f, 0.f, 0.f};

    // prologue
    STAGE(0, 0);
    asm volatile("s_waitcnt vmcnt(0)");
    __builtin_amdgcn_s_barrier();

// One K-tile: stage next->c^1, read frags from c, 16 MFMA, vmcnt(0), barrier.
// RAW: c staged last iter, drained by last iter's vmcnt(0)+barrier.
// WAR: stage into c^1 is >= one collective barrier after c^1's last read.
#define ITER(CC, TN) do {                                                      \
    STAGE(TN, (CC) ^ 1);                                                       \
    short8 af_[4], bf_[4];                                                     \
    _Pragma("unroll")                                                          \
    for (int i = 0; i < 4; ++i) af_[i] = RD8(&lA[CC][0], offA + i * 1024);     \
    _Pragma("unroll")                                                          \
    for (int n = 0; n < 4; ++n) bf_[n] = RD8(&lB[CC][0], offB + n * 1024);     \
    __builtin_amdgcn_s_setprio(1);                                             \
    _Pragma("unroll")                                                          \
    for (int i = 0; i < 4; ++i)                                                \
        _Pragma("unroll")                                                      \
        for (int n = 0; n < 4; ++n)                                            \
            acc[i][n] = __builtin_amdgcn_mfma_f32_16x16x32_bf16(af_[i], bf_[n], acc[i][n], 0, 0, 0); \
    __builtin_amdgcn_s_setprio(0);                                             \
    asm volatile("s_waitcnt vmcnt(0)");                                        \
    __builtin_amdgcn_s_barrier();                                              \
} while (0)

    for (int t = 0; t < 128; t += 2) {
        const int tn2 = (t + 2 < 128) ? t + 2 : 127;
        ITER(0, t + 1);
        ITER(1, tn2);
    }
#undef ITER
#undef STAGE

    // epilogue: relu(acc + be1) * We2, reduce over this wave's 64 d-cols
    const int cc = lane & 15, g = lane >> 4;
    float w2v[4], b1v[4];
#pragma unroll
    for (int ni = 0; ni < 4; ++ni) {
        const int d = dbase + wn * 64 + ni * 16 + cc;
        b1v[ni] = be1[e * H2_DIM + d];
        w2v[ni] = We2[e * H2_DIM + d];
    }
#pragma unroll
    for (int mi = 0; mi < 4; ++mi) {
#pragma unroll
        for (int r = 0; r < 4; ++r) {
            float s = 0.f;
#pragma unroll
            for (int ni = 0; ni < 4; ++ni) {
                float v = acc[mi][ni][r] + b1v[ni];
                v = fmaxf(v, 0.f);
                s = fmaf(v, w2v[ni], s);
            }
            s += __shfl_xor(s, 1);
            s += __shfl_xor(s, 2);
            s += __shfl_xor(s, 4);
            s += __shfl_xor(s, 8);
            if (cc == 0) red[wn][wm * 64 + mi * 16 + g * 4 + r] = s;
        }
    }
    __syncthreads();
    if (tid < 128) {
        const int b = bm * 128 + tid;
        epart[((size_t)b * E_DIM + e) * 8 + chunk] =
            red[0][tid] + red[1][tid] + red[2][tid] + red[3][tid];
    }
}

// ---------------------------------------------------------------------------
// Expert GEMM (fallback, fp32 in-kernel conversion) — round-1 verified.
// Writes epart [b][e][16].
// ---------------------------------------------------------------------------
__global__ __launch_bounds__(256, 2) void moe_expert_gemm(
    const float* __restrict__ x, const float* __restrict__ We1,
    const float* __restrict__ be1, const float* __restrict__ We2,
    float* __restrict__ epart)
{
    __shared__ short lA[128 * 64];
    __shared__ short lB[128 * 64];
    __shared__ float red[2][128];

    const int tid  = threadIdx.x;
    const int lane = tid & 63;
    const int wm   = (tid >> 6) >> 1;
    const int wn   = (tid >> 6) & 1;
    const int nb = blockIdx.x, bm = blockIdx.y;
    const int e = nb >> 4, chunk = nb & 15;
    const int dbase = chunk * 128;

    const float* Asrc = x + (size_t)bm * 128 * H_DIM;
    const float* Bsrc = We1 + (size_t)e * H_DIM * H2_DIM + dbase;

    f32x4 acc[4][4];
#pragma unroll
    for (int i = 0; i < 4; ++i)
#pragma unroll
        for (int j = 0; j < 4; ++j) acc[i][j] = (f32x4){0.f, 0.f, 0.f, 0.f};

    const int arow0 = tid >> 4, af4 = tid & 15;
    const int bn = tid & 127, bkc0 = tid >> 7;

    for (int k0 = 0; k0 < H_DIM; k0 += 64) {
        __syncthreads();
#pragma unroll
        for (int j = 0; j < 8; ++j) {
            const int row = arow0 + j * 16;
            const float* p = Asrc + (size_t)row * H_DIM + k0 + af4 * 4;
            float a0 = p[0], a1 = p[1], a2 = p[2], a3 = p[3];
            uint2 wv2;
            wv2.x = bf16_rn(a0) | (bf16_rn(a1) << 16);
            wv2.y = bf16_rn(a2) | (bf16_rn(a3) << 16);
            const int byte = row * 128 + ((af4 * 8) ^ ((row & 7) << 4));
            *reinterpret_cast<uint2*>(reinterpret_cast<char*>(lA) + byte) = wv2;
        }
#pragma unroll
        for (int j = 0; j < 4; ++j) {
            const int kc = bkc0 + 2 * j;
            const float* p = Bsrc + (size_t)(k0 + kc * 8) * H2_DIM + bn;
            uint4 wv4;
            wv4.x = bf16_rn(p[0])          | (bf16_rn(p[H2_DIM])     << 16);
            wv4.y = bf16_rn(p[2 * H2_DIM]) | (bf16_rn(p[3 * H2_DIM]) << 16);
            wv4.z = bf16_rn(p[4 * H2_DIM]) | (bf16_rn(p[5 * H2_DIM]) << 16);
            wv4.w = bf16_rn(p[6 * H2_DIM]) | (bf16_rn(p[7 * H2_DIM]) << 16);
            const int byte = bn * 128 + ((kc * 16) ^ ((bn & 7) << 4));
            *reinterpret_cast<uint4*>(reinterpret_cast<char*>(lB) + byte) = wv4;
        }
        __syncthreads();
#pragma unroll
        for (int kk = 0; kk < 2; ++kk) {
            const int kbyte = kk * 64 + ((lane >> 4) << 4);
            short8 af[4], bfr[4];
#pragma unroll
            for (int mi = 0; mi < 4; ++mi) {
                const int r = wm * 64 + mi * 16 + (lane & 15);
                af[mi] = *reinterpret_cast<const short8*>(
                    reinterpret_cast<const char*>(lA) + r * 128 + (kbyte ^ ((r & 7) << 4)));
            }
#pragma unroll
            for (int ni = 0; ni < 4; ++ni) {
                const int r = wn * 64 + ni * 16 + (lane & 15);
                bfr[ni] = *reinterpret_cast<const short8*>(
                    reinterpret_cast<const char*>(lB) + r * 128 + (kbyte ^ ((r & 7) << 4)));
            }
#pragma unroll
            for (int mi = 0; mi < 4; ++mi)
#pragma unroll
                for (int ni = 0; ni < 4; ++ni)
                    acc[mi][ni] = __builtin_amdgcn_mfma_f32_16x16x32_bf16(
                        af[mi], bfr[ni], acc[mi][ni], 0, 0, 0);
        }
    }

    const int c = lane & 15, g = lane >> 4;
    float w2v[4], b1v[4];
#pragma unroll
    for (int ni = 0; ni < 4; ++ni) {
        const int d = dbase + wn * 64 + ni * 16 + c;
        b1v[ni] = be1[e * H2_DIM + d];
        w2v[ni] = We2[e * H2_DIM + d];
    }
#pragma unroll
    for (int mi = 0; mi < 4; ++mi) {
#pragma unroll
        for (int r = 0; r < 4; ++r) {
            float s = 0.f;
#pragma unroll
            for (int ni = 0; ni < 4; ++ni) {
                float v = acc[mi][ni][r] + b1v[ni];
                v = fmaxf(v, 0.f);
                s = fmaf(v, w2v[ni], s);
            }
            s += __shfl_xor(s, 1);
            s += __shfl_xor(s, 2);
            s += __shfl_xor(s, 4);
            s += __shfl_xor(s, 8);
            if (c == 0) red[wn][wm * 64 + mi * 16 + g * 4 + r] = s;
        }
    }
    __syncthreads();
    if (tid < 128) {
        const int b = bm * 128 + tid;
        epart[((size_t)b * E_DIM + e) * 16 + chunk] = red[0][tid] + red[1][tid];
    }
}

// ---------------------------------------------------------------------------
// Gate GEMM, 3-term bf16 split for ~fp32 accuracy (top-k must match ref).
// ---------------------------------------------------------------------------
__global__ __launch_bounds__(256, 2) void moe_gate_gemm(
    const float* __restrict__ x, const float* __restrict__ Wg1,
    const float* __restrict__ bg1, const float* __restrict__ Wg2,
    float* __restrict__ gpart)
{
    __shared__ short lAh[128 * 64], lAl[128 * 64];
    __shared__ short lBh[128 * 64], lBl[128 * 64];
    __shared__ float lW2[128 * 8];
    __shared__ float gred[2][128][8];

    const int tid  = threadIdx.x;
    const int lane = tid & 63;
    const int wm = (tid >> 6) >> 1, wn = (tid >> 6) & 1;
    const int nb = blockIdx.x, bm = blockIdx.y;
    const int dbase = nb * 128;

    const float* Asrc = x + (size_t)bm * 128 * H_DIM;
    const float* Bsrc = Wg1 + dbase;

    {
        const f32x4* s = reinterpret_cast<const f32x4*>(Wg2 + (size_t)dbase * 8);
        reinterpret_cast<f32x4*>(lW2)[tid] = s[tid];
    }

    f32x4 acc[4][4];
#pragma unroll
    for (int i = 0; i < 4; ++i)
#pragma unroll
        for (int j = 0; j < 4; ++j) acc[i][j] = (f32x4){0.f, 0.f, 0.f, 0.f};

    const int arow0 = tid >> 4, af4 = tid & 15;
    const int bn = tid & 127, bkc0 = tid >> 7;

    for (int k0 = 0; k0 < H_DIM; k0 += 64) {
        __syncthreads();
#pragma unroll
        for (int j = 0; j < 8; ++j) {
            const int row = arow0 + j * 16;
            const float* p = Asrc + (size_t)row * H_DIM + k0 + af4 * 4;
            float a[4] = {p[0], p[1], p[2], p[3]};
            unsigned int hb[4], lb[4];
#pragma unroll
            for (int q = 0; q < 4; ++q) {
                hb[q] = bf16_rn(a[q]);
                lb[q] = bf16_rn(a[q] - bf16f(hb[q]));
            }
            const int byte = row * 128 + ((af4 * 8) ^ ((row & 7) << 4));
            *reinterpret_cast<uint2*>(reinterpret_cast<char*>(lAh) + byte) =
                make_uint2(hb[0] | (hb[1] << 16), hb[2] | (hb[3] << 16));
            *reinterpret_cast<uint2*>(reinterpret_cast<char*>(lAl) + byte) =
                make_uint2(lb[0] | (lb[1] << 16), lb[2] | (lb[3] << 16));
        }
#pragma unroll
        for (int j = 0; j < 4; ++j) {
            const int kc = bkc0 + 2 * j;
            const float* p = Bsrc + (size_t)(k0 + kc * 8) * H2_DIM + bn;
            unsigned int hb[8], lb[8];
#pragma unroll
            for (int q = 0; q < 8; ++q) {
                float v = p[(size_t)q * H2_DIM];
                hb[q] = bf16_rn(v);
                lb[q] = bf16_rn(v - bf16f(hb[q]));
            }
            const int byte = bn * 128 + ((kc * 16) ^ ((bn & 7) << 4));
            *reinterpret_cast<uint4*>(reinterpret_cast<char*>(lBh) + byte) =
                make_uint4(hb[0] | (hb[1] << 16), hb[2] | (hb[3] << 16),
                           hb[4] | (hb[5] << 16), hb[6] | (hb[7] << 16));
            *reinterpret_cast<uint4*>(reinterpret_cast<char*>(lBl) + byte) =
                make_uint4(lb[0] | (lb[1] << 16), lb[2] | (lb[3] << 16),
                           lb[4] | (lb[5] << 16), lb[6] | (lb[7] << 16));
        }
        __syncthreads();
#pragma unroll
        for (int kk = 0; kk < 2; ++kk) {
            const int kbyte = kk * 64 + ((lane >> 4) << 4);
            short8 ah[4], al[4], bh[4], bl[4];
#pragma unroll
            for (int mi = 0; mi < 4; ++mi) {
                const int r = wm * 64 + mi * 16 + (lane & 15);
                const int off = r * 128 + (kbyte ^ ((r & 7) << 4));
                ah[mi] = *reinterpret_cast<const short8*>(reinterpret_cast<const char*>(lAh) + off);
                al[mi] = *reinterpret_cast<const short8*>(reinterpret_cast<const char*>(lAl) + off);
            }
#pragma unroll
            for (int ni = 0; ni < 4; ++ni) {
                const int r = wn * 64 + ni * 16 + (lane & 15);
                const int off = r * 128 + (kbyte ^ ((r & 7) << 4));
                bh[ni] = *reinterpret_cast<const short8*>(reinterpret_cast<const char*>(lBh) + off);
                bl[ni] = *reinterpret_cast<const short8*>(reinterpret_cast<const char*>(lBl) + off);
            }
#pragma unroll
            for (int mi = 0; mi < 4; ++mi)
#pragma unroll
                for (int ni = 0; ni < 4; ++ni) {
                    acc[mi][ni] = __builtin_amdgcn_mfma_f32_16x16x32_bf16(ah[mi], bh[ni], acc[mi][ni], 0, 0, 0);
                    acc[mi][ni] = __builtin_amdgcn_mfma_f32_16x16x32_bf16(ah[mi], bl[ni], acc[mi][ni], 0, 0, 0);
                    acc[mi][ni] = __builtin_amdgcn_mfma_f32_16x16x32_bf16(al[mi], bh[ni], acc[mi][ni], 0, 0, 0);
                }
        }
    }

    const int c = lane & 15, g = lane >> 4;
    float bgv[4];
#pragma unroll
    for (int ni = 0; ni < 4; ++ni) bgv[ni] = bg1[dbase + wn * 64 + ni * 16 + c];
#pragma unroll
    for (int mi = 0; mi < 4; ++mi) {
#pragma unroll
        for (int r = 0; r < 4; ++r) {
            float gv[4];
#pragma unroll
            for (int ni = 0; ni < 4; ++ni)
                gv[ni] = fmaxf(acc[mi][ni][r] + bgv[ni], 0.f);
#pragma unroll
            for (int e8 = 0; e8 < 8; ++e8) {
                float t = 0.f;
#pragma unroll
                for (int ni = 0; ni < 4; ++ni)
                    t = fmaf(gv[ni], lW2[(wn * 64 + ni * 16 + c) * 8 + e8], t);
                t += __shfl_xor(t, 1);
                t += __shfl_xor(t, 2);
                t += __shfl_xor(t, 4);
                t += __shfl_xor(t, 8);
                if (c == e8) gred[wn][wm * 64 + mi * 16 + g * 4 + r][e8] = t;
            }
        }
    }
    __syncthreads();
    {
        const int row = tid & 127;
        const int ebase = (tid >> 7) * 4;
        const int b = bm * 128 + row;
#pragma unroll
        for (int i = 0; i < 4; ++i) {
            const int e8 = ebase + i;
            gpart[(size_t)b * 128 + nb * 8 + e8] = gred[0][row][e8] + gred[1][row][e8];
        }
    }
}

// ---------------------------------------------------------------------------
// Finalize: reduce partials, softmax top-2 (renormalized), combine.
// ---------------------------------------------------------------------------
template <int NC>
__global__ __launch_bounds__(256) void moe_finalize(
    const float* __restrict__ gpart, const float* __restrict__ epart,
    const float* __restrict__ bg2, const float* __restrict__ be2,
    float* __restrict__ out)
{
    const int b = blockIdx.x * 256 + threadIdx.x;
    float logit[8];
#pragma unroll
    for (int e = 0; e < 8; ++e) logit[e] = bg2[e];
    const float* gp = gpart + (size_t)b * 128;
#pragma unroll
    for (int cN = 0; cN < 16; ++cN)
#pragma unroll
        for (int e = 0; e < 8; ++e) logit[e] += gp[cN * 8 + e];

    float eo[8];
    const float* ep = epart + (size_t)b * E_DIM * NC;
#pragma unroll
    for (int e = 0; e < 8; ++e) {
        float s = be2[e];
#pragma unroll
        for (int cN = 0; cN < NC; ++cN) s += ep[e * NC + cN];
        eo[e] = s;
    }

    int i1 = 0; float m1 = logit[0];
#pragma unroll
    for (int e = 1; e < 8; ++e) if (logit[e] > m1) { m1 = logit[e]; i1 = e; }
    int i2 = -1; float m2 = -3.4e38f;
#pragma unroll
    for (int e = 0; e < 8; ++e) if (e != i1 && logit[e] > m2) { m2 = logit[e]; i2 = e; }

    const float w2 = expf(m2 - m1);
    out[b] = (eo[i1] + w2 * eo[i2]) / (1.f + w2);
}

// ---------------------------------------------------------------------------
extern "C" void kernel_launch(void* const* d_in, const int* in_sizes, int n_in,
                              void* d_out, int out_size, void* d_ws, size_t ws_size,
                              hipStream_t stream) {
    (void)in_sizes; (void)n_in; (void)out_size;
    const float* x   = (const float*)d_in[0];
    const float* We1 = (const float*)d_in[1];
    const float* be1 = (const float*)d_in[2];
    const float* We2 = (const float*)d_in[3];
    const float* be2 = (const float*)d_in[4];
    const float* Wg1 = (const float*)d_in[5];
    const float* bg1 = (const float*)d_in[6];
    const float* Wg2 = (const float*)d_in[7];
    const float* bg2 = (const float*)d_in[8];
    float* out = (float*)d_out;

    char* ws = (char*)d_ws;
    size_t off = 0;
    float* gpart = (float*)(ws + off);                 off += (size_t)B_DIM * 128 * 4;            // 8 MB
    float* epart = (float*)(ws + off);                 off += (size_t)B_DIM * 128 * 4;            // 8 MB
    unsigned short* panA = (unsigned short*)(ws + off); off += (size_t)B_DIM * H_DIM * 2;          // 128 MB
    unsigned short* panB = (unsigned short*)(ws + off); off += (size_t)E_DIM * H2_DIM * H_DIM * 2; // 128 MB
    const size_t NEED = off;

    if (ws_size >= NEED) {
        build_xA_panels<<<dim3(64, 64), 256, 0, stream>>>(x, panA);
        build_w1B_panels<<<dim3(32, 64, 8), 256, 0, stream>>>(We1, panB);
        moe_expert_gemm_128<<<8192, 512, 0, stream>>>(panA, panB, be1, We2, epart);
        moe_gate_gemm<<<dim3(16, 128), 256, 0, stream>>>(x, Wg1, bg1, Wg2, gpart);
        moe_finalize<8><<<64, 256, 0, stream>>>(gpart, epart, bg2, be2, out);
    } else {
        moe_expert_gemm<<<dim3(128, 128), 256, 0, stream>>>(x, We1, be1, We2, epart);
        moe_gate_gemm<<<dim3(16, 128), 256, 0, stream>>>(x, Wg1, bg1, Wg2, gpart);
        moe_finalize<16><<<64, 256, 0, stream>>>(gpart, epart, bg2, be2, out);
    }
}